// Round 6
// baseline (5184.664 us; speedup 1.0000x reference)
//
#include <hip/hip_runtime.h>
#include <hip/hip_bf16.h>

#define TT  512
#define BB  64
#define NII 1024
#define NHH 1024
#define NBLK 256

typedef __attribute__((ext_vector_type(8))) short bf16x8;
typedef __attribute__((ext_vector_type(4))) float f32x4;

#define WPK_BYTES (256ull * 64 * 64 * 8 * 2)     // 16 MiB packed weights
#define FLG_BYTES (4096ull)                      // 256 u32 flags (padded)
#define HBUF_SHORTS (65536ull)                   // one packed-H buffer = 128 KiB
#define HRING_BYTES (512ull * HBUF_SHORTS * 2)   // 64 MiB step-unique ring
#define HPP_BYTES   (2ull * HBUF_SHORTS * 2)     // 256 KiB ping-pong fallback
#define XPK_BYTES (512ull * HBUF_SHORTS * 2)     // 64 MiB packed x frags

#define MFMA16 __builtin_amdgcn_mfma_f32_16x16x32_bf16
#define LD_AG(p)    __hip_atomic_load((p),  __ATOMIC_RELAXED, __HIP_MEMORY_SCOPE_AGENT)
#define ST_AG(p, v) __hip_atomic_store((p), (v), __ATOMIC_RELAXED, __HIP_MEMORY_SCOPE_AGENT)

__device__ __forceinline__ float sigmoidf_(float x) { return 1.0f / (1.0f + __expf(-x)); }

__device__ __forceinline__ short f2bf(float f) {
    union { __hip_bfloat16 b; short s; } u; u.b = __float2bfloat16(f); return u.s;
}

// pipelined coherent 16B load: two relaxed agent-scope u64 atomics
__device__ __forceinline__ bf16x8 ld_coh16(const short* p) {
    const unsigned long long* q = (const unsigned long long*)p;
    unsigned long long a = LD_AG(q);
    unsigned long long b = LD_AG(q + 1);
    union { unsigned long long u[2]; bf16x8 v; } u;
    u.u[0] = a; u.u[1] = b; return u.v;
}

// ---------------------------------------------------------------------------
// Pack 8 weight matrices into MFMA-B-fragment-major bf16 (verified r2-r5).
// ---------------------------------------------------------------------------
__global__ __launch_bounds__(256)
void pack_weights_kernel(const float* __restrict__ Wxf, const float* __restrict__ Whf,
                         const float* __restrict__ Wxi, const float* __restrict__ Whi,
                         const float* __restrict__ Wxc, const float* __restrict__ Whc,
                         const float* __restrict__ Wxo, const float* __restrict__ Who,
                         short* __restrict__ wpk)
{
    const int b = blockIdx.x;
    const int t = threadIdx.x;
    const float* Wx[4] = { Wxf, Wxi, Wxc, Wxo };
    const float* Wh[4] = { Whf, Whi, Whc, Who };

    for (int i = 0; i < 16; ++i) {
        const int pair = t + i * 256;
        const int kk = pair >> 6;
        const int l  = pair & 63;
        const int n  = l & 15;
        const int g  = n >> 2;
        const int col = b * 4 + (n & 3);
        const int kf0 = kk * 32 + (l >> 4) * 8;
        const float* src = (kf0 < 1024) ? (Wx[g] + (size_t)kf0 * NHH + col)
                                        : (Wh[g] + (size_t)(kf0 - 1024) * NHH + col);
        short v[8];
        #pragma unroll
        for (int e = 0; e < 8; ++e) v[e] = f2bf(src[(size_t)e * NHH]);
        short* dst = wpk + ((size_t)(b * 64 + kk) * 64 + l) * 8;
        *reinterpret_cast<bf16x8*>(dst) = *reinterpret_cast<bf16x8*>(v);
    }
}

// ---------------------------------------------------------------------------
// Pack x into bf16 A-fragments: xpk[t][mi][kk][l][8] (verified r3-r5).
// ---------------------------------------------------------------------------
__global__ __launch_bounds__(256)
void pack_x_kernel(const float* __restrict__ x, short* __restrict__ xpk)
{
    const int t = blockIdx.x;
    const float* xt = x + (size_t)t * BB * NII;
    short* dst = xpk + (size_t)t * HBUF_SHORTS;

    for (int i = 0; i < 32; ++i) {
        const int d  = threadIdx.x + i * 256;
        const int mi = d >> 11;
        const int kk = (d >> 6) & 31;
        const int l  = d & 63;
        const int m  = mi * 16 + (l & 15);
        const int k0 = kk * 32 + ((l >> 4) << 3);
        const float* s = xt + (size_t)m * NII + k0;
        f32x4 a0 = *reinterpret_cast<const f32x4*>(s);
        f32x4 a1 = *reinterpret_cast<const f32x4*>(s + 4);
        short v[8];
        #pragma unroll
        for (int e = 0; e < 4; ++e) { v[e] = f2bf(a0[e]); v[4 + e] = f2bf(a1[e]); }
        *reinterpret_cast<bf16x8*>(dst + (size_t)d * 8) = *reinterpret_cast<bf16x8*>(v);
    }
}

// ---------------------------------------------------------------------------
// Persistent LSTM. 256 blocks x 512 threads, 1 block/CU (LDS-forced).
// Round-6 changes: s_sleep poll backoff; out/tail stores moved after the
// publish+flag so no HBM write-ack sits on the per-step serial chain.
// ---------------------------------------------------------------------------
__global__ __launch_bounds__(512, 1)
void lstm_persistent(const float* __restrict__ x,
                     const short* __restrict__ xpk,
                     const short* __restrict__ wpk,
                     const float* __restrict__ bfv, const float* __restrict__ biv,
                     const float* __restrict__ bcv, const float* __restrict__ bov,
                     float* __restrict__ out,
                     short* hbase,
                     unsigned* flags,
                     int hmode, int use_xpk)
{
    __shared__ short lds_w[64 * 64 * 8];   // 64 KiB weights, frag-major
    __shared__ float redx[4][64][4];
    __shared__ float redh[4][64][4];
    __shared__ float Cst[256];
    __shared__ short hstage[256];
    extern __shared__ char dynpad[];

    const int tid = threadIdx.x;
    const int w   = tid >> 6;
    const int l   = tid & 63;
    const int mi  = w & 3;
    const int kh  = w >> 2;
    const int b   = blockIdx.x;
    (void)dynpad;

    {
        const short* wsrc = wpk + (size_t)b * 32768;
        #pragma unroll
        for (int i = 0; i < 8; ++i) {
            const int c = tid + i * 512;
            *reinterpret_cast<bf16x8*>(&lds_w[c * 8]) =
                *reinterpret_cast<const bf16x8*>(&wsrc[(size_t)c * 8]);
        }
    }
    if (tid < 256) Cst[tid] = 0.0f;

    float B4[4] = {0.f, 0.f, 0.f, 0.f};
    if (tid < 256) {
        const int j = b * 4 + (tid & 3);
        B4[0] = bfv[j]; B4[1] = biv[j]; B4[2] = bcv[j]; B4[3] = bov[j];
    }
    __syncthreads();

    // packed-H write coords (j-range b*4..b*4+3 lies in one fragment octet)
    const int kk2 = b >> 3;
    const int lg  = (b >> 1) & 3;
    const int e0  = (b & 1) * 4;

    #pragma unroll 1
    for (int t = 0; t < TT; ++t) {
        const unsigned tv = (unsigned)t;
        const short* hcur = hbase + (size_t)(hmode ? t : (t & 1)) * HBUF_SHORTS;
        short*       hnxt = hbase + (size_t)(hmode ? (t + 1) : ((t + 1) & 1)) * HBUF_SHORTS;

        if (kh == 0) {
            f32x4 ac0 = {0,0,0,0}, ac1 = {0,0,0,0}, ac2 = {0,0,0,0}, ac3 = {0,0,0,0};
            const short* wl = &lds_w[(size_t)l * 8];
            if (use_xpk) {
                const short* ap = xpk + (size_t)t * HBUF_SHORTS + ((size_t)(mi * 32) * 64 + l) * 8;
                #pragma unroll 2
                for (int kk = 0; kk < 32; kk += 4) {
                    bf16x8 a0 = *reinterpret_cast<const bf16x8*>(ap);
                    bf16x8 b0 = *reinterpret_cast<const bf16x8*>(wl);
                    bf16x8 a1 = *reinterpret_cast<const bf16x8*>(ap + 512);
                    bf16x8 b1 = *reinterpret_cast<const bf16x8*>(wl + 512);
                    bf16x8 a2 = *reinterpret_cast<const bf16x8*>(ap + 1024);
                    bf16x8 b2 = *reinterpret_cast<const bf16x8*>(wl + 1024);
                    bf16x8 a3 = *reinterpret_cast<const bf16x8*>(ap + 1536);
                    bf16x8 b3 = *reinterpret_cast<const bf16x8*>(wl + 1536);
                    ac0 = MFMA16(a0, b0, ac0, 0, 0, 0);
                    ac1 = MFMA16(a1, b1, ac1, 0, 0, 0);
                    ac2 = MFMA16(a2, b2, ac2, 0, 0, 0);
                    ac3 = MFMA16(a3, b3, ac3, 0, 0, 0);
                    ap += 2048; wl += 2048;
                }
            } else {
                const float* apf = x + (size_t)t * BB * NII + (size_t)(mi * 16 + (l & 15)) * NII + (l >> 4) * 8;
                #pragma unroll 2
                for (int kk = 0; kk < 32; kk += 2) {
                    f32x4 a0 = *reinterpret_cast<const f32x4*>(apf);
                    f32x4 a1 = *reinterpret_cast<const f32x4*>(apf + 4);
                    bf16x8 b0 = *reinterpret_cast<const bf16x8*>(wl);
                    f32x4 a2 = *reinterpret_cast<const f32x4*>(apf + 32);
                    f32x4 a3 = *reinterpret_cast<const f32x4*>(apf + 36);
                    bf16x8 b1 = *reinterpret_cast<const bf16x8*>(wl + 512);
                    bf16x8 f0, f1;
                    f0[0]=f2bf(a0[0]); f0[1]=f2bf(a0[1]); f0[2]=f2bf(a0[2]); f0[3]=f2bf(a0[3]);
                    f0[4]=f2bf(a1[0]); f0[5]=f2bf(a1[1]); f0[6]=f2bf(a1[2]); f0[7]=f2bf(a1[3]);
                    f1[0]=f2bf(a2[0]); f1[1]=f2bf(a2[1]); f1[2]=f2bf(a2[2]); f1[3]=f2bf(a2[3]);
                    f1[4]=f2bf(a3[0]); f1[5]=f2bf(a3[1]); f1[6]=f2bf(a3[2]); f1[7]=f2bf(a3[3]);
                    ac0 = MFMA16(f0, b0, ac0, 0, 0, 0);
                    ac1 = MFMA16(f1, b1, ac1, 0, 0, 0);
                    apf += 64; wl += 1024;
                }
            }
            ac0[0]+=ac1[0]+ac2[0]+ac3[0]; ac0[1]+=ac1[1]+ac2[1]+ac3[1];
            ac0[2]+=ac1[2]+ac2[2]+ac3[2]; ac0[3]+=ac1[3]+ac2[3]+ac3[3];
            redx[mi][l][0]=ac0[0]; redx[mi][l][1]=ac0[1];
            redx[mi][l][2]=ac0[2]; redx[mi][l][3]=ac0[3];
        } else {
            // wait until every block has published H for this step.
            // s_sleep backoff: keeps the LLC coherence pipe clear so the
            // publishers' stores are not queued behind the poll storm.
            const unsigned long long* q = (const unsigned long long*)flags + l * 2;
            for (;;) {
                unsigned long long aa = LD_AG(q);
                unsigned long long bb = LD_AG(q + 1);
                int ok = ((unsigned)aa >= tv) & ((unsigned)(aa >> 32) >= tv) &
                         ((unsigned)bb >= tv) & ((unsigned)(bb >> 32) >= tv);
                if (__all(ok)) break;
                __builtin_amdgcn_s_sleep(2);
            }
            asm volatile("" ::: "memory");   // keep H loads below the poll

            f32x4 ac0 = {0,0,0,0}, ac1 = {0,0,0,0}, ac2 = {0,0,0,0}, ac3 = {0,0,0,0};
            const short* ap = hcur + ((size_t)(mi * 32) * 64 + l) * 8;
            const short* wl = &lds_w[((size_t)(32 * 64) + l) * 8];
            if (hmode) {
                #pragma unroll 2
                for (int kk = 0; kk < 32; kk += 4) {
                    bf16x8 a0 = *reinterpret_cast<const bf16x8*>(ap);
                    bf16x8 b0 = *reinterpret_cast<const bf16x8*>(wl);
                    bf16x8 a1 = *reinterpret_cast<const bf16x8*>(ap + 512);
                    bf16x8 b1 = *reinterpret_cast<const bf16x8*>(wl + 512);
                    bf16x8 a2 = *reinterpret_cast<const bf16x8*>(ap + 1024);
                    bf16x8 b2 = *reinterpret_cast<const bf16x8*>(wl + 1024);
                    bf16x8 a3 = *reinterpret_cast<const bf16x8*>(ap + 1536);
                    bf16x8 b3 = *reinterpret_cast<const bf16x8*>(wl + 1536);
                    ac0 = MFMA16(a0, b0, ac0, 0, 0, 0);
                    ac1 = MFMA16(a1, b1, ac1, 0, 0, 0);
                    ac2 = MFMA16(a2, b2, ac2, 0, 0, 0);
                    ac3 = MFMA16(a3, b3, ac3, 0, 0, 0);
                    ap += 2048; wl += 2048;
                }
            } else {
                #pragma unroll 2
                for (int kk = 0; kk < 32; kk += 4) {
                    bf16x8 a0 = ld_coh16(ap);
                    bf16x8 b0 = *reinterpret_cast<const bf16x8*>(wl);
                    bf16x8 a1 = ld_coh16(ap + 512);
                    bf16x8 b1 = *reinterpret_cast<const bf16x8*>(wl + 512);
                    bf16x8 a2 = ld_coh16(ap + 1024);
                    bf16x8 b2 = *reinterpret_cast<const bf16x8*>(wl + 1024);
                    bf16x8 a3 = ld_coh16(ap + 1536);
                    bf16x8 b3 = *reinterpret_cast<const bf16x8*>(wl + 1536);
                    ac0 = MFMA16(a0, b0, ac0, 0, 0, 0);
                    ac1 = MFMA16(a1, b1, ac1, 0, 0, 0);
                    ac2 = MFMA16(a2, b2, ac2, 0, 0, 0);
                    ac3 = MFMA16(a3, b3, ac3, 0, 0, 0);
                    ap += 2048; wl += 2048;
                }
            }
            ac0[0]+=ac1[0]+ac2[0]+ac3[0]; ac0[1]+=ac1[1]+ac2[1]+ac3[1];
            ac0[2]+=ac1[2]+ac2[2]+ac3[2]; ac0[3]+=ac1[3]+ac2[3]+ac3[3];
            redh[mi][l][0]=ac0[0]; redh[mi][l][1]=ac0[1];
            redh[mi][l][2]=ac0[2]; redh[mi][l][3]=ac0[3];
        }
        __syncthreads();

        // epilogue: LDS-only effects before the 2nd sync; hn/cn kept in regs
        float hn = 0.f, cn = 0.f;
        if (tid < 256) {
            const int m   = tid >> 2;
            const int jl  = tid & 3;
            const int mi2 = m >> 4, ml = m & 15;
            const int lr  = ml & 3;
            const int lb  = (ml >> 2) << 4;

            const float gf = redx[mi2][lb + jl][lr]      + redh[mi2][lb + jl][lr]      + B4[0];
            const float gi = redx[mi2][lb + 4 + jl][lr]  + redh[mi2][lb + 4 + jl][lr]  + B4[1];
            const float gc = redx[mi2][lb + 8 + jl][lr]  + redh[mi2][lb + 8 + jl][lr]  + B4[2];
            const float go = redx[mi2][lb + 12 + jl][lr] + redh[mi2][lb + 12 + jl][lr] + B4[3];

            const float F  = sigmoidf_(gf);
            const float I  = sigmoidf_(gi);
            const float Ct = tanhf(gc);
            const float O  = sigmoidf_(go);

            const float c = Cst[tid];
            cn = F * c + I * Ct;
            hn = O * tanhf(cn);
            Cst[tid]    = cn;
            hstage[tid] = f2bf(hn);
        }
        __syncthreads();

        // wave0: publish packed H + release flag. Only the 8B publish store
        // is outstanding at the vmcnt(0) -> minimal serial latency.
        if (w == 0 && t < TT - 1) {
            const int mi2 = l >> 4, ml = l & 15;
            const unsigned long long hv =
                *reinterpret_cast<const unsigned long long*>(&hstage[l * 4]);
            const size_t off = ((size_t)(mi2 * 32 + kk2) * 64 + lg * 16 + ml) * 8 + e0;
            ST_AG((unsigned long long*)(hnxt + off), hv);
            asm volatile("s_waitcnt vmcnt(0)" ::: "memory");
            if (l == 0)
                ST_AG(&flags[b], tv + 1u);
        }

        // out/tail stores AFTER the flag: write-acks drain at the next step's
        // barrier (~2 us later), fully off the serial chain.
        if (tid < 256) {
            const int m = tid >> 2;
            const int j = b * 4 + (tid & 3);
            __builtin_nontemporal_store(hn, &out[(size_t)t * BB * NHH + (size_t)m * NHH + j]);
            if (t == TT - 1) {
                float* tail = out + (size_t)TT * BB * NHH;
                tail[(size_t)m * NHH + j]                    = hn;
                tail[(size_t)BB * NHH + (size_t)m * NHH + j] = cn;
            }
        }
    }
}

extern "C" void kernel_launch(void* const* d_in, const int* in_sizes, int n_in,
                              void* d_out, int out_size, void* d_ws, size_t ws_size,
                              hipStream_t stream) {
    const float* inputs = (const float*)d_in[0];
    const float* Wxf = (const float*)d_in[1],  *Whf = (const float*)d_in[2],  *bf = (const float*)d_in[3];
    const float* Wxi = (const float*)d_in[4],  *Whi = (const float*)d_in[5],  *bi = (const float*)d_in[6];
    const float* Wxc = (const float*)d_in[7],  *Whc = (const float*)d_in[8],  *bc = (const float*)d_in[9];
    const float* Wxo = (const float*)d_in[10], *Who = (const float*)d_in[11], *bo = (const float*)d_in[12];

    float* out = (float*)d_out;
    char*  wsb = (char*)d_ws;

    short*    wpk   = (short*)wsb;
    unsigned* flags = (unsigned*)(wsb + WPK_BYTES);
    short*    hbase = (short*)(wsb + WPK_BYTES + FLG_BYTES);

    const size_t base = WPK_BYTES + FLG_BYTES;
    int hmode, use_xpk;
    short* xpk;
    if (ws_size >= base + HRING_BYTES + XPK_BYTES) {
        hmode = 1; use_xpk = 1; xpk = (short*)(wsb + base + HRING_BYTES);
    } else if (ws_size >= base + HRING_BYTES) {
        hmode = 1; use_xpk = 0; xpk = nullptr;
    } else if (ws_size >= base + HPP_BYTES + XPK_BYTES) {
        hmode = 0; use_xpk = 1; xpk = (short*)(wsb + base + HPP_BYTES);
    } else {
        hmode = 0; use_xpk = 0; xpk = nullptr;
    }

    // zero flags + H buffer 0 (adjacent) every launch
    hipMemsetAsync(flags, 0, FLG_BYTES + HBUF_SHORTS * 2, stream);

    pack_weights_kernel<<<dim3(256), dim3(256), 0, stream>>>(
        Wxf, Whf, Wxi, Whi, Wxc, Whc, Wxo, Who, wpk);

    if (use_xpk)
        pack_x_kernel<<<dim3(TT), dim3(256), 0, stream>>>(inputs, xpk);

    // 12 KiB dynamic LDS pad -> >80 KiB/block => 1 block/CU => 256 blocks
    // co-resident on 256 CUs (grid-wide flag sync is deadlock-free).
    lstm_persistent<<<dim3(NBLK), dim3(512), 12288, stream>>>(
        inputs, xpk, wpk, bf, bi, bc, bo, out, hbase, flags, hmode, use_xpk);
}

// Round 7
// 4153.114 us; speedup vs baseline: 1.2484x; 1.2484x over previous
//
#include <hip/hip_runtime.h>
#include <hip/hip_bf16.h>

#define TT  512
#define BB  64
#define NII 1024
#define NHH 1024
#define NBLK 256

typedef __attribute__((ext_vector_type(8))) short bf16x8;
typedef __attribute__((ext_vector_type(4))) float f32x4;

#define WPK_BYTES (256ull * 64 * 64 * 8 * 2)     // 16 MiB packed weights
#define FLG_BYTES (4096ull)                      // 256 u32 flags (padded)
#define HBUF_SHORTS (65536ull)                   // one packed-H buffer = 128 KiB
#define HRING_BYTES (512ull * HBUF_SHORTS * 2)   // 64 MiB step-unique ring
#define HPP_BYTES   (2ull * HBUF_SHORTS * 2)     // 256 KiB ping-pong fallback
#define XPK_BYTES (512ull * HBUF_SHORTS * 2)     // 64 MiB packed x frags

#define MFMA16 __builtin_amdgcn_mfma_f32_16x16x32_bf16
#define LD_AG(p)    __hip_atomic_load((p),  __ATOMIC_RELAXED, __HIP_MEMORY_SCOPE_AGENT)
#define ST_AG(p, v) __hip_atomic_store((p), (v), __ATOMIC_RELAXED, __HIP_MEMORY_SCOPE_AGENT)

__device__ __forceinline__ float fast_sigmoid(float x) {
    return __builtin_amdgcn_rcpf(1.0f + __expf(-x));
}
__device__ __forceinline__ float fast_tanh(float x) {
    // 1 - 2/(e^{2x}+1); exact at +-inf, ~1e-6 rel err, no branches
    float e = __expf(2.0f * x);
    return 1.0f - 2.0f * __builtin_amdgcn_rcpf(e + 1.0f);
}

__device__ __forceinline__ short f2bf(float f) {
    union { __hip_bfloat16 b; short s; } u; u.b = __float2bfloat16(f); return u.s;
}

// pipelined coherent 16B load: two relaxed agent-scope u64 atomics
__device__ __forceinline__ bf16x8 ld_coh16(const short* p) {
    const unsigned long long* q = (const unsigned long long*)p;
    unsigned long long a = LD_AG(q);
    unsigned long long b = LD_AG(q + 1);
    union { unsigned long long u[2]; bf16x8 v; } u;
    u.u[0] = a; u.u[1] = b; return u.v;
}

// ---------------------------------------------------------------------------
// Pack 8 weight matrices into MFMA-B-fragment-major bf16 (verified r2-r6).
// ---------------------------------------------------------------------------
__global__ __launch_bounds__(256)
void pack_weights_kernel(const float* __restrict__ Wxf, const float* __restrict__ Whf,
                         const float* __restrict__ Wxi, const float* __restrict__ Whi,
                         const float* __restrict__ Wxc, const float* __restrict__ Whc,
                         const float* __restrict__ Wxo, const float* __restrict__ Who,
                         short* __restrict__ wpk)
{
    const int b = blockIdx.x;
    const int t = threadIdx.x;
    const float* Wx[4] = { Wxf, Wxi, Wxc, Wxo };
    const float* Wh[4] = { Whf, Whi, Whc, Who };

    for (int i = 0; i < 16; ++i) {
        const int pair = t + i * 256;
        const int kk = pair >> 6;
        const int l  = pair & 63;
        const int n  = l & 15;
        const int g  = n >> 2;
        const int col = b * 4 + (n & 3);
        const int kf0 = kk * 32 + (l >> 4) * 8;
        const float* src = (kf0 < 1024) ? (Wx[g] + (size_t)kf0 * NHH + col)
                                        : (Wh[g] + (size_t)(kf0 - 1024) * NHH + col);
        short v[8];
        #pragma unroll
        for (int e = 0; e < 8; ++e) v[e] = f2bf(src[(size_t)e * NHH]);
        short* dst = wpk + ((size_t)(b * 64 + kk) * 64 + l) * 8;
        *reinterpret_cast<bf16x8*>(dst) = *reinterpret_cast<bf16x8*>(v);
    }
}

// ---------------------------------------------------------------------------
// Pack x into bf16 A-fragments: xpk[t][mi][kk][l][8] (verified r3-r6).
// ---------------------------------------------------------------------------
__global__ __launch_bounds__(256)
void pack_x_kernel(const float* __restrict__ x, short* __restrict__ xpk)
{
    const int t = blockIdx.x;
    const float* xt = x + (size_t)t * BB * NII;
    short* dst = xpk + (size_t)t * HBUF_SHORTS;

    for (int i = 0; i < 32; ++i) {
        const int d  = threadIdx.x + i * 256;
        const int mi = d >> 11;
        const int kk = (d >> 6) & 31;
        const int l  = d & 63;
        const int m  = mi * 16 + (l & 15);
        const int k0 = kk * 32 + ((l >> 4) << 3);
        const float* s = xt + (size_t)m * NII + k0;
        f32x4 a0 = *reinterpret_cast<const f32x4*>(s);
        f32x4 a1 = *reinterpret_cast<const f32x4*>(s + 4);
        short v[8];
        #pragma unroll
        for (int e = 0; e < 4; ++e) { v[e] = f2bf(a0[e]); v[4 + e] = f2bf(a1[e]); }
        *reinterpret_cast<bf16x8*>(dst + (size_t)d * 8) = *reinterpret_cast<bf16x8*>(v);
    }
}

// ---------------------------------------------------------------------------
// Persistent LSTM. 256 blocks x 512 threads, 1 block/CU (LDS-forced).
// Round-7: single global poller per block (wave 4) + LDS epoch relay for
// waves 5-7 -> 4x less flag-line pressure at the LLC; fast tanh/sigmoid.
// ---------------------------------------------------------------------------
__global__ __launch_bounds__(512, 1)
void lstm_persistent(const float* __restrict__ x,
                     const short* __restrict__ xpk,
                     const short* __restrict__ wpk,
                     const float* __restrict__ bfv, const float* __restrict__ biv,
                     const float* __restrict__ bcv, const float* __restrict__ bov,
                     float* __restrict__ out,
                     short* hbase,
                     unsigned* flags,
                     int hmode, int use_xpk)
{
    __shared__ short lds_w[64 * 64 * 8];   // 64 KiB weights, frag-major
    __shared__ float redx[4][64][4];
    __shared__ float redh[4][64][4];
    __shared__ float Cst[256];
    __shared__ short hstage[256];
    __shared__ int   lds_epoch;
    extern __shared__ char dynpad[];

    const int tid = threadIdx.x;
    const int w   = tid >> 6;
    const int l   = tid & 63;
    const int mi  = w & 3;
    const int kh  = w >> 2;
    const int b   = blockIdx.x;
    (void)dynpad;

    {
        const short* wsrc = wpk + (size_t)b * 32768;
        #pragma unroll
        for (int i = 0; i < 8; ++i) {
            const int c = tid + i * 512;
            *reinterpret_cast<bf16x8*>(&lds_w[c * 8]) =
                *reinterpret_cast<const bf16x8*>(&wsrc[(size_t)c * 8]);
        }
    }
    if (tid < 256) Cst[tid] = 0.0f;
    if (tid == 0)  lds_epoch = 0;

    float B4[4] = {0.f, 0.f, 0.f, 0.f};
    if (tid < 256) {
        const int j = b * 4 + (tid & 3);
        B4[0] = bfv[j]; B4[1] = biv[j]; B4[2] = bcv[j]; B4[3] = bov[j];
    }
    __syncthreads();

    // packed-H write coords (j-range b*4..b*4+3 lies in one fragment octet)
    const int kk2 = b >> 3;
    const int lg  = (b >> 1) & 3;
    const int e0  = (b & 1) * 4;

    #pragma unroll 1
    for (int t = 0; t < TT; ++t) {
        const unsigned tv = (unsigned)t;
        const short* hcur = hbase + (size_t)(hmode ? t : (t & 1)) * HBUF_SHORTS;
        short*       hnxt = hbase + (size_t)(hmode ? (t + 1) : ((t + 1) & 1)) * HBUF_SHORTS;

        if (kh == 0) {
            f32x4 ac0 = {0,0,0,0}, ac1 = {0,0,0,0}, ac2 = {0,0,0,0}, ac3 = {0,0,0,0};
            const short* wl = &lds_w[(size_t)l * 8];
            if (use_xpk) {
                const short* ap = xpk + (size_t)t * HBUF_SHORTS + ((size_t)(mi * 32) * 64 + l) * 8;
                #pragma unroll 2
                for (int kk = 0; kk < 32; kk += 4) {
                    bf16x8 a0 = *reinterpret_cast<const bf16x8*>(ap);
                    bf16x8 b0 = *reinterpret_cast<const bf16x8*>(wl);
                    bf16x8 a1 = *reinterpret_cast<const bf16x8*>(ap + 512);
                    bf16x8 b1 = *reinterpret_cast<const bf16x8*>(wl + 512);
                    bf16x8 a2 = *reinterpret_cast<const bf16x8*>(ap + 1024);
                    bf16x8 b2 = *reinterpret_cast<const bf16x8*>(wl + 1024);
                    bf16x8 a3 = *reinterpret_cast<const bf16x8*>(ap + 1536);
                    bf16x8 b3 = *reinterpret_cast<const bf16x8*>(wl + 1536);
                    ac0 = MFMA16(a0, b0, ac0, 0, 0, 0);
                    ac1 = MFMA16(a1, b1, ac1, 0, 0, 0);
                    ac2 = MFMA16(a2, b2, ac2, 0, 0, 0);
                    ac3 = MFMA16(a3, b3, ac3, 0, 0, 0);
                    ap += 2048; wl += 2048;
                }
            } else {
                const float* apf = x + (size_t)t * BB * NII + (size_t)(mi * 16 + (l & 15)) * NII + (l >> 4) * 8;
                #pragma unroll 2
                for (int kk = 0; kk < 32; kk += 2) {
                    f32x4 a0 = *reinterpret_cast<const f32x4*>(apf);
                    f32x4 a1 = *reinterpret_cast<const f32x4*>(apf + 4);
                    bf16x8 b0 = *reinterpret_cast<const bf16x8*>(wl);
                    f32x4 a2 = *reinterpret_cast<const f32x4*>(apf + 32);
                    f32x4 a3 = *reinterpret_cast<const f32x4*>(apf + 36);
                    bf16x8 b1 = *reinterpret_cast<const bf16x8*>(wl + 512);
                    bf16x8 f0, f1;
                    f0[0]=f2bf(a0[0]); f0[1]=f2bf(a0[1]); f0[2]=f2bf(a0[2]); f0[3]=f2bf(a0[3]);
                    f0[4]=f2bf(a1[0]); f0[5]=f2bf(a1[1]); f0[6]=f2bf(a1[2]); f0[7]=f2bf(a1[3]);
                    f1[0]=f2bf(a2[0]); f1[1]=f2bf(a2[1]); f1[2]=f2bf(a2[2]); f1[3]=f2bf(a2[3]);
                    f1[4]=f2bf(a3[0]); f1[5]=f2bf(a3[1]); f1[6]=f2bf(a3[2]); f1[7]=f2bf(a3[3]);
                    ac0 = MFMA16(f0, b0, ac0, 0, 0, 0);
                    ac1 = MFMA16(f1, b1, ac1, 0, 0, 0);
                    apf += 64; wl += 1024;
                }
            }
            ac0[0]+=ac1[0]+ac2[0]+ac3[0]; ac0[1]+=ac1[1]+ac2[1]+ac3[1];
            ac0[2]+=ac1[2]+ac2[2]+ac3[2]; ac0[3]+=ac1[3]+ac2[3]+ac3[3];
            redx[mi][l][0]=ac0[0]; redx[mi][l][1]=ac0[1];
            redx[mi][l][2]=ac0[2]; redx[mi][l][3]=ac0[3];
        } else {
            // ---- H-ready wait ----
            if (mi == 0) {
                // wave 4: the block's ONLY global poller (256 pollers total,
                // ~0.37 req/cy/line at the LLC -> no queueing storm)
                const unsigned long long* q = (const unsigned long long*)flags + l * 2;
                for (;;) {
                    unsigned long long aa = LD_AG(q);
                    unsigned long long bb = LD_AG(q + 1);
                    int ok = ((unsigned)aa >= tv) & ((unsigned)(aa >> 32) >= tv) &
                             ((unsigned)bb >= tv) & ((unsigned)(bb >> 32) >= tv);
                    if (__all(ok)) break;
                    __builtin_amdgcn_s_sleep(1);
                }
                if (l == 0) *((volatile int*)&lds_epoch) = t;   // relay
            } else {
                // waves 5-7: cheap LDS spin on the relayed epoch
                while (*((volatile int*)&lds_epoch) < t) { }
            }
            asm volatile("" ::: "memory");   // keep H loads below the wait

            f32x4 ac0 = {0,0,0,0}, ac1 = {0,0,0,0}, ac2 = {0,0,0,0}, ac3 = {0,0,0,0};
            const short* ap = hcur + ((size_t)(mi * 32) * 64 + l) * 8;
            const short* wl = &lds_w[((size_t)(32 * 64) + l) * 8];
            if (hmode) {
                #pragma unroll 2
                for (int kk = 0; kk < 32; kk += 4) {
                    bf16x8 a0 = *reinterpret_cast<const bf16x8*>(ap);
                    bf16x8 b0 = *reinterpret_cast<const bf16x8*>(wl);
                    bf16x8 a1 = *reinterpret_cast<const bf16x8*>(ap + 512);
                    bf16x8 b1 = *reinterpret_cast<const bf16x8*>(wl + 512);
                    bf16x8 a2 = *reinterpret_cast<const bf16x8*>(ap + 1024);
                    bf16x8 b2 = *reinterpret_cast<const bf16x8*>(wl + 1024);
                    bf16x8 a3 = *reinterpret_cast<const bf16x8*>(ap + 1536);
                    bf16x8 b3 = *reinterpret_cast<const bf16x8*>(wl + 1536);
                    ac0 = MFMA16(a0, b0, ac0, 0, 0, 0);
                    ac1 = MFMA16(a1, b1, ac1, 0, 0, 0);
                    ac2 = MFMA16(a2, b2, ac2, 0, 0, 0);
                    ac3 = MFMA16(a3, b3, ac3, 0, 0, 0);
                    ap += 2048; wl += 2048;
                }
            } else {
                #pragma unroll 2
                for (int kk = 0; kk < 32; kk += 4) {
                    bf16x8 a0 = ld_coh16(ap);
                    bf16x8 b0 = *reinterpret_cast<const bf16x8*>(wl);
                    bf16x8 a1 = ld_coh16(ap + 512);
                    bf16x8 b1 = *reinterpret_cast<const bf16x8*>(wl + 512);
                    bf16x8 a2 = ld_coh16(ap + 1024);
                    bf16x8 b2 = *reinterpret_cast<const bf16x8*>(wl + 1024);
                    bf16x8 a3 = ld_coh16(ap + 1536);
                    bf16x8 b3 = *reinterpret_cast<const bf16x8*>(wl + 1536);
                    ac0 = MFMA16(a0, b0, ac0, 0, 0, 0);
                    ac1 = MFMA16(a1, b1, ac1, 0, 0, 0);
                    ac2 = MFMA16(a2, b2, ac2, 0, 0, 0);
                    ac3 = MFMA16(a3, b3, ac3, 0, 0, 0);
                    ap += 2048; wl += 2048;
                }
            }
            ac0[0]+=ac1[0]+ac2[0]+ac3[0]; ac0[1]+=ac1[1]+ac2[1]+ac3[1];
            ac0[2]+=ac1[2]+ac2[2]+ac3[2]; ac0[3]+=ac1[3]+ac2[3]+ac3[3];
            redh[mi][l][0]=ac0[0]; redh[mi][l][1]=ac0[1];
            redh[mi][l][2]=ac0[2]; redh[mi][l][3]=ac0[3];
        }
        __syncthreads();

        // epilogue: LDS-only effects before the 2nd sync; hn/cn kept in regs
        float hn = 0.f, cn = 0.f;
        if (tid < 256) {
            const int m   = tid >> 2;
            const int jl  = tid & 3;
            const int mi2 = m >> 4, ml = m & 15;
            const int lr  = ml & 3;
            const int lb  = (ml >> 2) << 4;

            const float gf = redx[mi2][lb + jl][lr]      + redh[mi2][lb + jl][lr]      + B4[0];
            const float gi = redx[mi2][lb + 4 + jl][lr]  + redh[mi2][lb + 4 + jl][lr]  + B4[1];
            const float gc = redx[mi2][lb + 8 + jl][lr]  + redh[mi2][lb + 8 + jl][lr]  + B4[2];
            const float go = redx[mi2][lb + 12 + jl][lr] + redh[mi2][lb + 12 + jl][lr] + B4[3];

            const float F  = fast_sigmoid(gf);
            const float I  = fast_sigmoid(gi);
            const float Ct = fast_tanh(gc);
            const float O  = fast_sigmoid(go);

            const float c = Cst[tid];
            cn = F * c + I * Ct;
            hn = O * fast_tanh(cn);
            Cst[tid]    = cn;
            hstage[tid] = f2bf(hn);
        }
        __syncthreads();

        // wave0: publish packed H + release flag. Only the 8B publish store
        // is outstanding at the vmcnt(0) -> minimal serial latency.
        if (w == 0 && t < TT - 1) {
            const int mi2 = l >> 4, ml = l & 15;
            const unsigned long long hv =
                *reinterpret_cast<const unsigned long long*>(&hstage[l * 4]);
            const size_t off = ((size_t)(mi2 * 32 + kk2) * 64 + lg * 16 + ml) * 8 + e0;
            ST_AG((unsigned long long*)(hnxt + off), hv);
            asm volatile("s_waitcnt vmcnt(0)" ::: "memory");
            if (l == 0)
                ST_AG(&flags[b], tv + 1u);
        }

        // out/tail stores AFTER the flag: write-acks drain off the chain
        if (tid < 256) {
            const int m = tid >> 2;
            const int j = b * 4 + (tid & 3);
            __builtin_nontemporal_store(hn, &out[(size_t)t * BB * NHH + (size_t)m * NHH + j]);
            if (t == TT - 1) {
                float* tail = out + (size_t)TT * BB * NHH;
                tail[(size_t)m * NHH + j]                    = hn;
                tail[(size_t)BB * NHH + (size_t)m * NHH + j] = cn;
            }
        }
    }
}

extern "C" void kernel_launch(void* const* d_in, const int* in_sizes, int n_in,
                              void* d_out, int out_size, void* d_ws, size_t ws_size,
                              hipStream_t stream) {
    const float* inputs = (const float*)d_in[0];
    const float* Wxf = (const float*)d_in[1],  *Whf = (const float*)d_in[2],  *bf = (const float*)d_in[3];
    const float* Wxi = (const float*)d_in[4],  *Whi = (const float*)d_in[5],  *bi = (const float*)d_in[6];
    const float* Wxc = (const float*)d_in[7],  *Whc = (const float*)d_in[8],  *bc = (const float*)d_in[9];
    const float* Wxo = (const float*)d_in[10], *Who = (const float*)d_in[11], *bo = (const float*)d_in[12];

    float* out = (float*)d_out;
    char*  wsb = (char*)d_ws;

    short*    wpk   = (short*)wsb;
    unsigned* flags = (unsigned*)(wsb + WPK_BYTES);
    short*    hbase = (short*)(wsb + WPK_BYTES + FLG_BYTES);

    const size_t base = WPK_BYTES + FLG_BYTES;
    int hmode, use_xpk;
    short* xpk;
    if (ws_size >= base + HRING_BYTES + XPK_BYTES) {
        hmode = 1; use_xpk = 1; xpk = (short*)(wsb + base + HRING_BYTES);
    } else if (ws_size >= base + HRING_BYTES) {
        hmode = 1; use_xpk = 0; xpk = nullptr;
    } else if (ws_size >= base + HPP_BYTES + XPK_BYTES) {
        hmode = 0; use_xpk = 1; xpk = (short*)(wsb + base + HPP_BYTES);
    } else {
        hmode = 0; use_xpk = 0; xpk = nullptr;
    }

    // zero flags + H buffer 0 (adjacent) every launch
    hipMemsetAsync(flags, 0, FLG_BYTES + HBUF_SHORTS * 2, stream);

    pack_weights_kernel<<<dim3(256), dim3(256), 0, stream>>>(
        Wxf, Whf, Wxi, Whi, Wxc, Whc, Wxo, Who, wpk);

    if (use_xpk)
        pack_x_kernel<<<dim3(TT), dim3(256), 0, stream>>>(inputs, xpk);

    // 12 KiB dynamic LDS pad -> >80 KiB/block => 1 block/CU => 256 blocks
    // co-resident on 256 CUs (grid-wide flag sync is deadlock-free).
    lstm_persistent<<<dim3(NBLK), dim3(512), 12288, stream>>>(
        inputs, xpk, wpk, bf, bi, bc, bo, out, hbase, flags, hmode, use_xpk);
}

// Round 8
// 3893.470 us; speedup vs baseline: 1.3316x; 1.0667x over previous
//
#include <hip/hip_runtime.h>
#include <hip/hip_bf16.h>

#define TT  512
#define BB  64
#define NII 1024
#define NHH 1024
#define NBLK 256

typedef __attribute__((ext_vector_type(8))) short bf16x8;
typedef __attribute__((ext_vector_type(4))) float f32x4;
typedef unsigned long long u64;

// ws layout: [wpk 16M][flags 4K][ring 64M][xpk 64M]
#define WPK_BYTES  (16ull << 20)                 // 128 c-blocks x 128 KiB
#define FLG_BYTES  (4096ull)                     // 2 domains x 128 u32 (padded)
#define RING_BYTES (64ull << 20)                 // 512 t x 2 s x 64 KiB packed H
#define XPK_BYTES  (64ull << 20)                 // 512 t x 128 KiB packed x
#define RING_T_SHORTS 32768ull                   // shorts per (t,s) buffer

#define MFMA16 __builtin_amdgcn_mfma_f32_16x16x32_bf16
#define LD_AG(p)    __hip_atomic_load((p),  __ATOMIC_RELAXED, __HIP_MEMORY_SCOPE_AGENT)
#define ST_AG(p, v) __hip_atomic_store((p), (v), __ATOMIC_RELAXED, __HIP_MEMORY_SCOPE_AGENT)

__device__ __forceinline__ float fast_sigmoid(float x) {
    return __builtin_amdgcn_rcpf(1.0f + __expf(-x));
}
__device__ __forceinline__ float fast_tanh(float x) {
    float e = __expf(2.0f * x);
    return 1.0f - 2.0f * __builtin_amdgcn_rcpf(e + 1.0f);
}
__device__ __forceinline__ short f2bf(float f) {
    union { __hip_bfloat16 b; short s; } u; u.b = __float2bfloat16(f); return u.s;
}

// ---------------------------------------------------------------------------
// Pack weights, B-fragment-major bf16, 32 gate-cols per c-block.
// chunk d = (kk_f*2 + nt)*64 + l ; element e:
//   W_fused[kk_f*32 + (l>>4)*8 + e][gatecol n = nt*16 + (l&15)]
//   gate = n>>3, col = c*8 + (n&7); fused K: x rows 0..1023, h rows 1024..2047
// ---------------------------------------------------------------------------
__global__ __launch_bounds__(256)
void pack_weights_kernel(const float* __restrict__ Wxf, const float* __restrict__ Whf,
                         const float* __restrict__ Wxi, const float* __restrict__ Whi,
                         const float* __restrict__ Wxc, const float* __restrict__ Whc,
                         const float* __restrict__ Wxo, const float* __restrict__ Who,
                         short* __restrict__ wpk)
{
    const int c = blockIdx.x;                 // 0..127
    const int t = threadIdx.x;
    const float* Wx[4] = { Wxf, Wxi, Wxc, Wxo };
    const float* Wh[4] = { Whf, Whi, Whc, Who };

    for (int i = 0; i < 32; ++i) {
        const int d   = t + i * 256;          // 0..8191 = (kk_f, nt, l)
        const int kkf = d >> 7;
        const int nt  = (d >> 6) & 1;
        const int l   = d & 63;
        const int n   = nt * 16 + (l & 15);   // 0..31
        const int g   = n >> 3;
        const int col = c * 8 + (n & 7);
        const int kf0 = kkf * 32 + (l >> 4) * 8;
        const float* src = (kf0 < 1024) ? (Wx[g] + (size_t)kf0 * NHH + col)
                                        : (Wh[g] + (size_t)(kf0 - 1024) * NHH + col);
        short v[8];
        #pragma unroll
        for (int e = 0; e < 8; ++e) v[e] = f2bf(src[(size_t)e * NHH]);
        *reinterpret_cast<bf16x8*>(wpk + ((size_t)c * 8192 + d) * 8) =
            *reinterpret_cast<bf16x8*>(v);
    }
}

// ---------------------------------------------------------------------------
// Pack x into per-half A-fragments: chunk d = ((s*2+mi)*32+kk)*64 + l
//   element = x[t][s*32 + mi*16 + (l&15)][kk*32 + (l>>4)*8 + e]
// ---------------------------------------------------------------------------
__global__ __launch_bounds__(256)
void pack_x_kernel(const float* __restrict__ x, short* __restrict__ xpk)
{
    const int t = blockIdx.x;
    const float* xt = x + (size_t)t * BB * NII;
    short* dst = xpk + (size_t)t * 65536;

    for (int i = 0; i < 32; ++i) {
        const int d  = threadIdx.x + i * 256;  // 0..8191
        const int s  = d >> 12;
        const int mi = (d >> 11) & 1;
        const int kk = (d >> 6) & 31;
        const int l  = d & 63;
        const int m  = s * 32 + mi * 16 + (l & 15);
        const int k0 = kk * 32 + ((l >> 4) << 3);
        const float* sp = xt + (size_t)m * NII + k0;
        f32x4 a0 = *reinterpret_cast<const f32x4*>(sp);
        f32x4 a1 = *reinterpret_cast<const f32x4*>(sp + 4);
        short v[8];
        #pragma unroll
        for (int e = 0; e < 4; ++e) { v[e] = f2bf(a0[e]); v[4 + e] = f2bf(a1[e]); }
        *reinterpret_cast<bf16x8*>(dst + (size_t)d * 8) = *reinterpret_cast<bf16x8*>(v);
    }
}

// ---------------------------------------------------------------------------
// Persistent LSTM, round-8 geometry:
//  256 blocks x 256 threads (4 waves), 1 block/CU (139.8 KiB static LDS).
//  Block (c = bx>>1, s = bx&1): 32 batches (half s) x 32 gate-cols (8 hid x 4 g).
//  Waves: w = kh*2 + mi. kh=0 -> x-half (no wait); kh=1 -> h-half (poll 128
//  flags of domain s). Weights (128 KiB) in LDS. C-state & biases in VGPRs.
// ---------------------------------------------------------------------------
__global__ __launch_bounds__(256, 1)
void lstm_persistent(const float* __restrict__ x,
                     const short* __restrict__ xpk,
                     const short* __restrict__ wpk,
                     const float* __restrict__ bfv, const float* __restrict__ biv,
                     const float* __restrict__ bcv, const float* __restrict__ bov,
                     float* __restrict__ out,
                     short* ring,
                     unsigned* flags,
                     int use_xpk)
{
    __shared__ short lds_w[64 * 2 * 64 * 8];   // 128 KiB weights
    __shared__ float red[4][64][8];            // per-wave C/D partials (8 KiB)
    __shared__ short hstage[256];              // bf16 H staging (512 B)

    const int tid = threadIdx.x;
    const int w   = tid >> 6;
    const int l   = tid & 63;
    const int mi  = w & 1;
    const int kh  = w >> 1;
    const int c   = blockIdx.x >> 1;           // 0..127
    const int s   = blockIdx.x & 1;            // batch half

    unsigned* flags_s = flags + s * 512;       // 128 u32 per domain, 2 KiB apart

    // stage this block's 128 KiB weight slice into LDS
    {
        const short* wsrc = wpk + (size_t)c * 65536;
        #pragma unroll
        for (int i = 0; i < 32; ++i) {
            const int ch = tid + i * 256;
            *reinterpret_cast<bf16x8*>(&lds_w[(size_t)ch * 8]) =
                *reinterpret_cast<const bf16x8*>(&wsrc[(size_t)ch * 8]);
        }
    }

    // epilogue-thread constants (every thread is an epilogue thread)
    const int m_loc = tid >> 3;                // 0..31
    const int jc    = tid & 7;                 // hidden col within block
    const int mi2   = m_loc >> 4, ml = m_loc & 15;
    const int lb    = (ml >> 2) << 4, lr = ml & 3;
    const int jcol  = c * 8 + jc;
    const int mrow  = s * 32 + m_loc;

    float B4[4];
    B4[0] = bfv[jcol]; B4[1] = biv[jcol]; B4[2] = bcv[jcol]; B4[3] = bov[jcol];
    float cstate = 0.0f;
    __syncthreads();

    #pragma unroll 1
    for (int t = 0; t < TT; ++t) {
        const short* rcur = ring + ((size_t)t * 2 + s) * RING_T_SHORTS;
        short*       rnxt = ring + ((size_t)(t + 1) * 2 + s) * RING_T_SHORTS;

        f32x4 a00 = {0,0,0,0}, a01 = {0,0,0,0}, a10 = {0,0,0,0}, a11 = {0,0,0,0};
        const short* wl = &lds_w[((size_t)(kh * 32) * 2) * 512 + (size_t)l * 8];

        if (kh == 0) {
            if (use_xpk) {
                const short* ap = xpk + (size_t)t * 65536
                                + (((size_t)(s * 2 + mi)) * 32) * 512 + (size_t)l * 8;
                #pragma unroll 4
                for (int kk = 0; kk < 32; kk += 2) {
                    bf16x8 A0  = *reinterpret_cast<const bf16x8*>(ap);
                    bf16x8 B00 = *reinterpret_cast<const bf16x8*>(wl);
                    bf16x8 B01 = *reinterpret_cast<const bf16x8*>(wl + 512);
                    bf16x8 A1  = *reinterpret_cast<const bf16x8*>(ap + 512);
                    bf16x8 B10 = *reinterpret_cast<const bf16x8*>(wl + 1024);
                    bf16x8 B11 = *reinterpret_cast<const bf16x8*>(wl + 1536);
                    a00 = MFMA16(A0, B00, a00, 0, 0, 0);
                    a01 = MFMA16(A0, B01, a01, 0, 0, 0);
                    a10 = MFMA16(A1, B10, a10, 0, 0, 0);
                    a11 = MFMA16(A1, B11, a11, 0, 0, 0);
                    ap += 1024; wl += 2048;
                }
            } else {
                const float* apf = x + ((size_t)t * BB + (size_t)(s * 32 + mi * 16 + (l & 15))) * NII
                                 + ((l >> 4) << 3);
                #pragma unroll 4
                for (int kk = 0; kk < 32; kk += 2) {
                    f32x4 f0 = *reinterpret_cast<const f32x4*>(apf);
                    f32x4 f1 = *reinterpret_cast<const f32x4*>(apf + 4);
                    bf16x8 B00 = *reinterpret_cast<const bf16x8*>(wl);
                    bf16x8 B01 = *reinterpret_cast<const bf16x8*>(wl + 512);
                    f32x4 f2 = *reinterpret_cast<const f32x4*>(apf + 32);
                    f32x4 f3 = *reinterpret_cast<const f32x4*>(apf + 36);
                    bf16x8 B10 = *reinterpret_cast<const bf16x8*>(wl + 1024);
                    bf16x8 B11 = *reinterpret_cast<const bf16x8*>(wl + 1536);
                    bf16x8 A0, A1;
                    A0[0]=f2bf(f0[0]); A0[1]=f2bf(f0[1]); A0[2]=f2bf(f0[2]); A0[3]=f2bf(f0[3]);
                    A0[4]=f2bf(f1[0]); A0[5]=f2bf(f1[1]); A0[6]=f2bf(f1[2]); A0[7]=f2bf(f1[3]);
                    A1[0]=f2bf(f2[0]); A1[1]=f2bf(f2[1]); A1[2]=f2bf(f2[2]); A1[3]=f2bf(f2[3]);
                    A1[4]=f2bf(f3[0]); A1[5]=f2bf(f3[1]); A1[6]=f2bf(f3[2]); A1[7]=f2bf(f3[3]);
                    a00 = MFMA16(A0, B00, a00, 0, 0, 0);
                    a01 = MFMA16(A0, B01, a01, 0, 0, 0);
                    a10 = MFMA16(A1, B10, a10, 0, 0, 0);
                    a11 = MFMA16(A1, B11, a11, 0, 0, 0);
                    apf += 64; wl += 2048;
                }
            }
        } else {
            // poll this domain's 128 flags: one u64 per lane
            const u64* q = (const u64*)flags_s;
            for (;;) {
                u64 v = LD_AG(q + l);
                int ok = ((unsigned)v >= (unsigned)t) & ((unsigned)(v >> 32) >= (unsigned)t);
                if (__all(ok)) break;
                __builtin_amdgcn_s_sleep(1);
            }
            asm volatile("" ::: "memory");   // keep H loads below the poll

            const short* ap = rcur + ((size_t)(mi * 32)) * 512 + (size_t)l * 8;
            #pragma unroll 4
            for (int kk = 0; kk < 32; kk += 2) {
                bf16x8 A0  = *reinterpret_cast<const bf16x8*>(ap);
                bf16x8 B00 = *reinterpret_cast<const bf16x8*>(wl);
                bf16x8 B01 = *reinterpret_cast<const bf16x8*>(wl + 512);
                bf16x8 A1  = *reinterpret_cast<const bf16x8*>(ap + 512);
                bf16x8 B10 = *reinterpret_cast<const bf16x8*>(wl + 1024);
                bf16x8 B11 = *reinterpret_cast<const bf16x8*>(wl + 1536);
                a00 = MFMA16(A0, B00, a00, 0, 0, 0);
                a01 = MFMA16(A0, B01, a01, 0, 0, 0);
                a10 = MFMA16(A1, B10, a10, 0, 0, 0);
                a11 = MFMA16(A1, B11, a11, 0, 0, 0);
                ap += 1024; wl += 2048;
            }
        }
        // combine parity accumulators: nt0 = a00+a10, nt1 = a01+a11
        {
            float* r = &red[w][l][0];
            r[0] = a00[0] + a10[0]; r[1] = a00[1] + a10[1];
            r[2] = a00[2] + a10[2]; r[3] = a00[3] + a10[3];
            r[4] = a01[0] + a11[0]; r[5] = a01[1] + a11[1];
            r[6] = a01[2] + a11[2]; r[7] = a01[3] + a11[3];
        }
        __syncthreads();

        // epilogue: all 256 threads, one (m_loc, jc) each; C in registers
        float gv[4];
        #pragma unroll
        for (int g = 0; g < 4; ++g) {
            const int lane = lb + (g & 1) * 8 + jc;   // C/D col = (g*8+jc)&15
            const int e    = (g >> 1) * 4 + lr;       // nt*4 + row&3
            gv[g] = red[mi2][lane][e] + red[2 + mi2][lane][e] + B4[g];
        }
        const float F  = fast_sigmoid(gv[0]);
        const float I  = fast_sigmoid(gv[1]);
        const float Ct = fast_tanh(gv[2]);
        const float O  = fast_sigmoid(gv[3]);
        cstate = F * cstate + I * Ct;
        const float hn = O * fast_tanh(cstate);
        hstage[tid] = f2bf(hn);
        __syncthreads();

        // wave0 lanes 0..31 publish 16B each (coherent), then release flag
        if (w == 0 && t < TT - 1) {
            if (l < 32) {
                const int mi3 = l >> 4, ml3 = l & 15;
                const u64 v0 = ((const u64*)hstage)[l * 2];
                const u64 v1 = ((const u64*)hstage)[l * 2 + 1];
                const size_t sh = ((size_t)(mi3 * 32 + (c >> 2)) * 64
                                   + (size_t)((c & 3) * 16 + ml3)) * 8;
                u64* dq = (u64*)(rnxt + sh);
                ST_AG(dq, v0);
                ST_AG(dq + 1, v1);
            }
            asm volatile("s_waitcnt vmcnt(0)" ::: "memory");
            if (tid == 0)
                ST_AG(&flags_s[c], (unsigned)(t + 1));
        }

        // out/tail stores off the serial chain
        __builtin_nontemporal_store(hn, &out[(size_t)t * BB * NHH + (size_t)mrow * NHH + jcol]);
        if (t == TT - 1) {
            float* tail = out + (size_t)TT * BB * NHH;
            tail[(size_t)mrow * NHH + jcol]                    = hn;
            tail[(size_t)BB * NHH + (size_t)mrow * NHH + jcol] = cstate;
        }
    }
}

extern "C" void kernel_launch(void* const* d_in, const int* in_sizes, int n_in,
                              void* d_out, int out_size, void* d_ws, size_t ws_size,
                              hipStream_t stream) {
    const float* inputs = (const float*)d_in[0];
    const float* Wxf = (const float*)d_in[1],  *Whf = (const float*)d_in[2],  *bf = (const float*)d_in[3];
    const float* Wxi = (const float*)d_in[4],  *Whi = (const float*)d_in[5],  *bi = (const float*)d_in[6];
    const float* Wxc = (const float*)d_in[7],  *Whc = (const float*)d_in[8],  *bc = (const float*)d_in[9];
    const float* Wxo = (const float*)d_in[10], *Who = (const float*)d_in[11], *bo = (const float*)d_in[12];

    float* out = (float*)d_out;
    char*  wsb = (char*)d_ws;

    short*    wpk   = (short*)wsb;
    unsigned* flags = (unsigned*)(wsb + WPK_BYTES);
    short*    ring  = (short*)(wsb + WPK_BYTES + FLG_BYTES);
    short*    xpk   = (short*)(wsb + WPK_BYTES + FLG_BYTES + RING_BYTES);

    const size_t need = WPK_BYTES + FLG_BYTES + RING_BYTES + XPK_BYTES;
    const int use_xpk = (ws_size >= need) ? 1 : 0;

    // zero flags (4K) + ring[t=0] both halves (128K) every launch
    hipMemsetAsync(flags, 0, FLG_BYTES + 2 * RING_T_SHORTS * sizeof(short), stream);

    pack_weights_kernel<<<dim3(128), dim3(256), 0, stream>>>(
        Wxf, Whf, Wxi, Whi, Wxc, Whc, Wxo, Who, wpk);

    if (use_xpk)
        pack_x_kernel<<<dim3(TT), dim3(256), 0, stream>>>(inputs, xpk);

    // 139.8 KiB static LDS -> 1 block/CU -> all 256 blocks co-resident;
    // two independent 128-block sync domains (batch halves).
    lstm_persistent<<<dim3(NBLK), dim3(256), 0, stream>>>(
        inputs, xpk, wpk, bf, bi, bc, bo, out, ring, flags, use_xpk);
}

// Round 9
// 3586.277 us; speedup vs baseline: 1.4457x; 1.0857x over previous
//
#include <hip/hip_runtime.h>
#include <hip/hip_bf16.h>

#define TT  512
#define BB  64
#define NII 1024
#define NHH 1024
#define NBLK 256

typedef __attribute__((ext_vector_type(8))) short bf16x8;
typedef __attribute__((ext_vector_type(4))) float f32x4;
typedef unsigned long long u64;

// ws layout: [wpk 16M][flags 16K][hpp 256K][xpk 64M]
#define WPK_BYTES  (16ull << 20)            // 128 c-blocks x 128 KiB packed W
#define FLG_BYTES  (16384ull)               // 2 domains x 128 flags x 64 B
#define HPP_BYTES  (256ull << 10)           // 2 parity x 2 domains x 64 KiB H
#define XPK_BYTES  (64ull << 20)            // 512 t x 128 KiB packed x
#define HBUF_SHORTS 32768ull                // shorts per (parity, s) H buffer

#define MFMA16 __builtin_amdgcn_mfma_f32_16x16x32_bf16
#define LD_AG(p)    __hip_atomic_load((p),  __ATOMIC_RELAXED, __HIP_MEMORY_SCOPE_AGENT)
#define ST_AG(p, v) __hip_atomic_store((p), (v), __ATOMIC_RELAXED, __HIP_MEMORY_SCOPE_AGENT)

__device__ __forceinline__ float fast_sigmoid(float x) {
    return __builtin_amdgcn_rcpf(1.0f + __expf(-x));
}
__device__ __forceinline__ float fast_tanh(float x) {
    float e = __expf(2.0f * x);
    return 1.0f - 2.0f * __builtin_amdgcn_rcpf(e + 1.0f);
}
__device__ __forceinline__ short f2bf(float f) {
    union { __hip_bfloat16 b; short s; } u; u.b = __float2bfloat16(f); return u.s;
}

// pipelined coherent 16B load: two relaxed agent-scope u64 atomics (bypass
// stale L2, no per-load waitcnt drain)
__device__ __forceinline__ bf16x8 ld_coh16(const short* p) {
    const u64* q = (const u64*)p;
    u64 a = LD_AG(q);
    u64 b = LD_AG(q + 1);
    union { u64 u[2]; bf16x8 v; } u;
    u.u[0] = a; u.u[1] = b; return u.v;
}

// ---------------------------------------------------------------------------
// Pack weights, B-fragment-major bf16, 32 gate-cols per c-block (verified r8).
// ---------------------------------------------------------------------------
__global__ __launch_bounds__(256)
void pack_weights_kernel(const float* __restrict__ Wxf, const float* __restrict__ Whf,
                         const float* __restrict__ Wxi, const float* __restrict__ Whi,
                         const float* __restrict__ Wxc, const float* __restrict__ Whc,
                         const float* __restrict__ Wxo, const float* __restrict__ Who,
                         short* __restrict__ wpk)
{
    const int c = blockIdx.x;                 // 0..127
    const int t = threadIdx.x;
    const float* Wx[4] = { Wxf, Wxi, Wxc, Wxo };
    const float* Wh[4] = { Whf, Whi, Whc, Who };

    for (int i = 0; i < 32; ++i) {
        const int d   = t + i * 256;          // (kk_f, nt, l)
        const int kkf = d >> 7;
        const int nt  = (d >> 6) & 1;
        const int l   = d & 63;
        const int n   = nt * 16 + (l & 15);
        const int g   = n >> 3;
        const int col = c * 8 + (n & 7);
        const int kf0 = kkf * 32 + (l >> 4) * 8;
        const float* src = (kf0 < 1024) ? (Wx[g] + (size_t)kf0 * NHH + col)
                                        : (Wh[g] + (size_t)(kf0 - 1024) * NHH + col);
        short v[8];
        #pragma unroll
        for (int e = 0; e < 8; ++e) v[e] = f2bf(src[(size_t)e * NHH]);
        *reinterpret_cast<bf16x8*>(wpk + ((size_t)c * 8192 + d) * 8) =
            *reinterpret_cast<bf16x8*>(v);
    }
}

// ---------------------------------------------------------------------------
// Pack x into per-half A-fragments (verified r8).
// ---------------------------------------------------------------------------
__global__ __launch_bounds__(256)
void pack_x_kernel(const float* __restrict__ x, short* __restrict__ xpk)
{
    const int t = blockIdx.x;
    const float* xt = x + (size_t)t * BB * NII;
    short* dst = xpk + (size_t)t * 65536;

    for (int i = 0; i < 32; ++i) {
        const int d  = threadIdx.x + i * 256;
        const int s  = d >> 12;
        const int mi = (d >> 11) & 1;
        const int kk = (d >> 6) & 31;
        const int l  = d & 63;
        const int m  = s * 32 + mi * 16 + (l & 15);
        const int k0 = kk * 32 + ((l >> 4) << 3);
        const float* sp = xt + (size_t)m * NII + k0;
        f32x4 a0 = *reinterpret_cast<const f32x4*>(sp);
        f32x4 a1 = *reinterpret_cast<const f32x4*>(sp + 4);
        short v[8];
        #pragma unroll
        for (int e = 0; e < 4; ++e) { v[e] = f2bf(a0[e]); v[4 + e] = f2bf(a1[e]); }
        *reinterpret_cast<bf16x8*>(dst + (size_t)d * 8) = *reinterpret_cast<bf16x8*>(v);
    }
}

// ---------------------------------------------------------------------------
// x-half compute for one wave (mi) at timestep t -> writes 8 floats to rdst.
// ---------------------------------------------------------------------------
__device__ __forceinline__ void compute_x_half(
    int t, int mi, int l, int s, int use_xpk,
    const float* __restrict__ x, const short* __restrict__ xpk,
    const short* lds_w, float* rdst)
{
    f32x4 a00 = {0,0,0,0}, a01 = {0,0,0,0}, a10 = {0,0,0,0}, a11 = {0,0,0,0};
    const short* wl = lds_w + (size_t)l * 8;            // kh=0 weight base
    if (use_xpk) {
        const short* ap = xpk + (size_t)t * 65536
                        + (((size_t)(s * 2 + mi)) * 32) * 512 + (size_t)l * 8;
        #pragma unroll 4
        for (int kk = 0; kk < 32; kk += 2) {
            bf16x8 A0  = *reinterpret_cast<const bf16x8*>(ap);
            bf16x8 B00 = *reinterpret_cast<const bf16x8*>(wl);
            bf16x8 B01 = *reinterpret_cast<const bf16x8*>(wl + 512);
            bf16x8 A1  = *reinterpret_cast<const bf16x8*>(ap + 512);
            bf16x8 B10 = *reinterpret_cast<const bf16x8*>(wl + 1024);
            bf16x8 B11 = *reinterpret_cast<const bf16x8*>(wl + 1536);
            a00 = MFMA16(A0, B00, a00, 0, 0, 0);
            a01 = MFMA16(A0, B01, a01, 0, 0, 0);
            a10 = MFMA16(A1, B10, a10, 0, 0, 0);
            a11 = MFMA16(A1, B11, a11, 0, 0, 0);
            ap += 1024; wl += 2048;
        }
    } else {
        const float* apf = x + ((size_t)t * BB + (size_t)(s * 32 + mi * 16 + (l & 15))) * NII
                         + ((l >> 4) << 3);
        #pragma unroll 4
        for (int kk = 0; kk < 32; kk += 2) {
            f32x4 f0 = *reinterpret_cast<const f32x4*>(apf);
            f32x4 f1 = *reinterpret_cast<const f32x4*>(apf + 4);
            bf16x8 B00 = *reinterpret_cast<const bf16x8*>(wl);
            bf16x8 B01 = *reinterpret_cast<const bf16x8*>(wl + 512);
            f32x4 f2 = *reinterpret_cast<const f32x4*>(apf + 32);
            f32x4 f3 = *reinterpret_cast<const f32x4*>(apf + 36);
            bf16x8 B10 = *reinterpret_cast<const bf16x8*>(wl + 1024);
            bf16x8 B11 = *reinterpret_cast<const bf16x8*>(wl + 1536);
            bf16x8 A0, A1;
            A0[0]=f2bf(f0[0]); A0[1]=f2bf(f0[1]); A0[2]=f2bf(f0[2]); A0[3]=f2bf(f0[3]);
            A0[4]=f2bf(f1[0]); A0[5]=f2bf(f1[1]); A0[6]=f2bf(f1[2]); A0[7]=f2bf(f1[3]);
            A1[0]=f2bf(f2[0]); A1[1]=f2bf(f2[1]); A1[2]=f2bf(f2[2]); A1[3]=f2bf(f2[3]);
            A1[4]=f2bf(f3[0]); A1[5]=f2bf(f3[1]); A1[6]=f2bf(f3[2]); A1[7]=f2bf(f3[3]);
            a00 = MFMA16(A0, B00, a00, 0, 0, 0);
            a01 = MFMA16(A0, B01, a01, 0, 0, 0);
            a10 = MFMA16(A1, B10, a10, 0, 0, 0);
            a11 = MFMA16(A1, B11, a11, 0, 0, 0);
            apf += 64; wl += 2048;
        }
    }
    rdst[0] = a00[0] + a10[0]; rdst[1] = a00[1] + a10[1];
    rdst[2] = a00[2] + a10[2]; rdst[3] = a00[3] + a10[3];
    rdst[4] = a01[0] + a11[0]; rdst[5] = a01[1] + a11[1];
    rdst[6] = a01[2] + a11[2]; rdst[7] = a01[3] + a11[3];
}

// ---------------------------------------------------------------------------
// Persistent LSTM, round-9:
//  - x computed ONE STEP AHEAD into double-buffered redx (off critical path)
//  - H exchange via 256 KB ping-pong (LLC-hot) + agent-atomic loads
//  - single poller wave + LDS epoch relay; flags spaced 64 B
// ---------------------------------------------------------------------------
__global__ __launch_bounds__(256, 1)
void lstm_persistent(const float* __restrict__ x,
                     const short* __restrict__ xpk,
                     const short* __restrict__ wpk,
                     const float* __restrict__ bfv, const float* __restrict__ biv,
                     const float* __restrict__ bcv, const float* __restrict__ bov,
                     float* __restrict__ out,
                     short* hpp,
                     unsigned* flags,
                     int use_xpk)
{
    __shared__ short lds_w[64 * 2 * 64 * 8];   // 128 KiB weights
    __shared__ float redx[2][2][64][8];        // [buf][x-wave mi][l][8]  8 KiB
    __shared__ float redh[2][64][8];           // [h-wave mi][l][8]       4 KiB
    __shared__ short hstage[256];
    __shared__ int   lds_epoch;

    const int tid = threadIdx.x;
    const int w   = tid >> 6;
    const int l   = tid & 63;
    const int mi  = w & 1;
    const int kh  = w >> 1;
    const int c   = blockIdx.x >> 1;           // 0..127
    const int s   = blockIdx.x & 1;            // batch-half domain

    unsigned* flags_s = flags + s * 2048;      // 128 flags x 16 u32 stride

    {
        const short* wsrc = wpk + (size_t)c * 65536;
        #pragma unroll
        for (int i = 0; i < 32; ++i) {
            const int ch = tid + i * 256;
            *reinterpret_cast<bf16x8*>(&lds_w[(size_t)ch * 8]) =
                *reinterpret_cast<const bf16x8*>(&wsrc[(size_t)ch * 8]);
        }
    }
    if (tid == 0) lds_epoch = -1;

    const int m_loc = tid >> 3;
    const int jc    = tid & 7;
    const int mi2   = m_loc >> 4, ml = m_loc & 15;
    const int lb    = (ml >> 2) << 4, lr = ml & 3;
    const int jcol  = c * 8 + jc;
    const int mrow  = s * 32 + m_loc;

    float B4[4];
    B4[0] = bfv[jcol]; B4[1] = biv[jcol]; B4[2] = bcv[jcol]; B4[3] = bov[jcol];
    float cstate = 0.0f;
    __syncthreads();

    // prologue: x-waves fill redx[0] with x(0)
    if (kh == 0)
        compute_x_half(0, mi, l, s, use_xpk, x, xpk, lds_w, &redx[0][mi][l][0]);

    #pragma unroll 1
    for (int t = 0; t < TT; ++t) {
        const short* rcur = hpp + ((size_t)((t & 1) * 2 + s)) * HBUF_SHORTS;
        short*       rnxt = hpp + ((size_t)(((t + 1) & 1) * 2 + s)) * HBUF_SHORTS;

        if (kh == 1) {
            if (mi == 0) {
                // wave 2: the block's only global poller
                const unsigned tv = (unsigned)t;
                for (;;) {
                    unsigned v0 = LD_AG(flags_s + (size_t)l * 16);
                    unsigned v1 = LD_AG(flags_s + (size_t)(l + 64) * 16);
                    if (__all((v0 >= tv) & (v1 >= tv))) break;
                    __builtin_amdgcn_s_sleep(1);
                }
                if (l == 0) *((volatile int*)&lds_epoch) = t;   // relay
            } else {
                // wave 3: cheap LDS spin
                while (*((volatile int*)&lds_epoch) < t) { }
            }
            asm volatile("" ::: "memory");   // keep H loads below the wait

            f32x4 a00 = {0,0,0,0}, a01 = {0,0,0,0}, a10 = {0,0,0,0}, a11 = {0,0,0,0};
            const short* ap = rcur + ((size_t)(mi * 32)) * 512 + (size_t)l * 8;
            const short* wl = &lds_w[(size_t)32768 + (size_t)l * 8];
            #pragma unroll 4
            for (int kk = 0; kk < 32; kk += 2) {
                bf16x8 A0  = ld_coh16(ap);
                bf16x8 B00 = *reinterpret_cast<const bf16x8*>(wl);
                bf16x8 B01 = *reinterpret_cast<const bf16x8*>(wl + 512);
                bf16x8 A1  = ld_coh16(ap + 512);
                bf16x8 B10 = *reinterpret_cast<const bf16x8*>(wl + 1024);
                bf16x8 B11 = *reinterpret_cast<const bf16x8*>(wl + 1536);
                a00 = MFMA16(A0, B00, a00, 0, 0, 0);
                a01 = MFMA16(A0, B01, a01, 0, 0, 0);
                a10 = MFMA16(A1, B10, a10, 0, 0, 0);
                a11 = MFMA16(A1, B11, a11, 0, 0, 0);
                ap += 1024; wl += 2048;
            }
            float* r = &redh[mi][l][0];
            r[0] = a00[0] + a10[0]; r[1] = a00[1] + a10[1];
            r[2] = a00[2] + a10[2]; r[3] = a00[3] + a10[3];
            r[4] = a01[0] + a11[0]; r[5] = a01[1] + a11[1];
            r[6] = a01[2] + a11[2]; r[7] = a01[3] + a11[3];
        } else {
            // x-waves: prefetch-compute x(t+1) (HBM misses hide under h-chain)
            if (t + 1 < TT)
                compute_x_half(t + 1, mi, l, s, use_xpk, x, xpk, lds_w,
                               &redx[(t + 1) & 1][mi][l][0]);
        }
        __syncthreads();

        // epilogue: all 256 threads; C in registers
        const float (*rx)[64][8] = redx[t & 1];
        float gv[4];
        #pragma unroll
        for (int g = 0; g < 4; ++g) {
            const int lane = lb + (g & 1) * 8 + jc;
            const int e    = (g >> 1) * 4 + lr;
            gv[g] = rx[mi2][lane][e] + redh[mi2][lane][e] + B4[g];
        }
        const float F  = fast_sigmoid(gv[0]);
        const float I  = fast_sigmoid(gv[1]);
        const float Ct = fast_tanh(gv[2]);
        const float O  = fast_sigmoid(gv[3]);
        cstate = F * cstate + I * Ct;
        const float hn = O * fast_tanh(cstate);
        hstage[tid] = f2bf(hn);
        __syncthreads();

        // wave0 lanes 0..31 publish 16B each (coherent), then release flag
        if (w == 0 && t < TT - 1) {
            if (l < 32) {
                const int mi3 = l >> 4, ml3 = l & 15;
                const u64 v0 = ((const u64*)hstage)[l * 2];
                const u64 v1 = ((const u64*)hstage)[l * 2 + 1];
                const size_t sh = ((size_t)(mi3 * 32 + (c >> 2)) * 64
                                   + (size_t)((c & 3) * 16 + ml3)) * 8;
                u64* dq = (u64*)(rnxt + sh);
                ST_AG(dq, v0);
                ST_AG(dq + 1, v1);
            }
            asm volatile("s_waitcnt vmcnt(0)" ::: "memory");
            if (tid == 0)
                ST_AG(&flags_s[(size_t)c * 16], (unsigned)(t + 1));
        }

        // out/tail stores off the serial chain
        __builtin_nontemporal_store(hn, &out[(size_t)t * BB * NHH + (size_t)mrow * NHH + jcol]);
        if (t == TT - 1) {
            float* tail = out + (size_t)TT * BB * NHH;
            tail[(size_t)mrow * NHH + jcol]                    = hn;
            tail[(size_t)BB * NHH + (size_t)mrow * NHH + jcol] = cstate;
        }
    }
}

extern "C" void kernel_launch(void* const* d_in, const int* in_sizes, int n_in,
                              void* d_out, int out_size, void* d_ws, size_t ws_size,
                              hipStream_t stream) {
    const float* inputs = (const float*)d_in[0];
    const float* Wxf = (const float*)d_in[1],  *Whf = (const float*)d_in[2],  *bf = (const float*)d_in[3];
    const float* Wxi = (const float*)d_in[4],  *Whi = (const float*)d_in[5],  *bi = (const float*)d_in[6];
    const float* Wxc = (const float*)d_in[7],  *Whc = (const float*)d_in[8],  *bc = (const float*)d_in[9];
    const float* Wxo = (const float*)d_in[10], *Who = (const float*)d_in[11], *bo = (const float*)d_in[12];

    float* out = (float*)d_out;
    char*  wsb = (char*)d_ws;

    short*    wpk   = (short*)wsb;
    unsigned* flags = (unsigned*)(wsb + WPK_BYTES);
    short*    hpp   = (short*)(wsb + WPK_BYTES + FLG_BYTES);
    short*    xpk   = (short*)(wsb + WPK_BYTES + FLG_BYTES + HPP_BYTES);

    const size_t need = WPK_BYTES + FLG_BYTES + HPP_BYTES + XPK_BYTES;
    const int use_xpk = (ws_size >= need) ? 1 : 0;

    // zero flags (16K) + whole H ping-pong (256K) every launch
    hipMemsetAsync(flags, 0, FLG_BYTES + HPP_BYTES, stream);

    pack_weights_kernel<<<dim3(128), dim3(256), 0, stream>>>(
        Wxf, Whf, Wxi, Whi, Wxc, Whc, Wxo, Who, wpk);

    if (use_xpk)
        pack_x_kernel<<<dim3(TT), dim3(256), 0, stream>>>(inputs, xpk);

    // ~140.5 KiB static LDS -> 1 block/CU -> 256 blocks co-resident;
    // two independent 128-block sync domains (batch halves).
    lstm_persistent<<<dim3(NBLK), dim3(256), 0, stream>>>(
        inputs, xpk, wpk, bf, bi, bc, bo, out, hpp, flags, use_xpk);
}

// Round 10
// 3494.172 us; speedup vs baseline: 1.4838x; 1.0264x over previous
//
#include <hip/hip_runtime.h>
#include <hip/hip_bf16.h>

#define TT  512
#define BB  64
#define NII 1024
#define NHH 1024
#define NBLK 256

typedef __attribute__((ext_vector_type(8))) short bf16x8;
typedef __attribute__((ext_vector_type(4))) float f32x4;
typedef unsigned long long u64;

// ws layout: [wpk 16M][flags 16K][hpp 256K][xpk 64M][gx 256M]
#define WPK_BYTES  (16ull << 20)
#define FLG_BYTES  (16384ull)
#define HPP_BYTES  (256ull << 10)
#define XPK_BYTES  (64ull << 20)
#define GX_BYTES   (256ull << 20)           // 512t x 2s x 128c x 2mi x 64l x 8 bf16
#define HBUF_SHORTS 32768ull

#define MFMA16 __builtin_amdgcn_mfma_f32_16x16x32_bf16
#define LD_AG(p)    __hip_atomic_load((p),  __ATOMIC_RELAXED, __HIP_MEMORY_SCOPE_AGENT)
#define ST_AG(p, v) __hip_atomic_store((p), (v), __ATOMIC_RELAXED, __HIP_MEMORY_SCOPE_AGENT)

__device__ __forceinline__ float fast_sigmoid(float x) {
    return __builtin_amdgcn_rcpf(1.0f + __expf(-x));
}
__device__ __forceinline__ float fast_tanh(float x) {
    float e = __expf(2.0f * x);
    return 1.0f - 2.0f * __builtin_amdgcn_rcpf(e + 1.0f);
}
__device__ __forceinline__ short f2bf(float f) {
    union { __hip_bfloat16 b; short s; } u; u.b = __float2bfloat16(f); return u.s;
}
__device__ __forceinline__ float bf2f(short h) {
    union { unsigned u; float f; } v; v.u = ((unsigned)(unsigned short)h) << 16; return v.f;
}

// pipelined coherent 16B load: two relaxed agent-scope u64 atomics
__device__ __forceinline__ bf16x8 ld_coh16(const short* p) {
    const u64* q = (const u64*)p;
    u64 a = LD_AG(q);
    u64 b = LD_AG(q + 1);
    union { u64 u[2]; bf16x8 v; } u;
    u.u[0] = a; u.u[1] = b; return u.v;
}

// ---------------------------------------------------------------------------
// Pack weights, B-fragment-major bf16, 32 gate-cols per c-block (verified r8/r9).
// ---------------------------------------------------------------------------
__global__ __launch_bounds__(256)
void pack_weights_kernel(const float* __restrict__ Wxf, const float* __restrict__ Whf,
                         const float* __restrict__ Wxi, const float* __restrict__ Whi,
                         const float* __restrict__ Wxc, const float* __restrict__ Whc,
                         const float* __restrict__ Wxo, const float* __restrict__ Who,
                         short* __restrict__ wpk)
{
    const int c = blockIdx.x;
    const int t = threadIdx.x;
    const float* Wx[4] = { Wxf, Wxi, Wxc, Wxo };
    const float* Wh[4] = { Whf, Whi, Whc, Who };

    for (int i = 0; i < 32; ++i) {
        const int d   = t + i * 256;
        const int kkf = d >> 7;
        const int nt  = (d >> 6) & 1;
        const int l   = d & 63;
        const int n   = nt * 16 + (l & 15);
        const int g   = n >> 3;
        const int col = c * 8 + (n & 7);
        const int kf0 = kkf * 32 + (l >> 4) * 8;
        const float* src = (kf0 < 1024) ? (Wx[g] + (size_t)kf0 * NHH + col)
                                        : (Wh[g] + (size_t)(kf0 - 1024) * NHH + col);
        short v[8];
        #pragma unroll
        for (int e = 0; e < 8; ++e) v[e] = f2bf(src[(size_t)e * NHH]);
        *reinterpret_cast<bf16x8*>(wpk + ((size_t)c * 8192 + d) * 8) =
            *reinterpret_cast<bf16x8*>(v);
    }
}

// ---------------------------------------------------------------------------
// Pack x into per-half A-fragments (verified r8/r9).
// ---------------------------------------------------------------------------
__global__ __launch_bounds__(256)
void pack_x_kernel(const float* __restrict__ x, short* __restrict__ xpk)
{
    const int t = blockIdx.x;
    const float* xt = x + (size_t)t * BB * NII;
    short* dst = xpk + (size_t)t * 65536;

    for (int i = 0; i < 32; ++i) {
        const int d  = threadIdx.x + i * 256;
        const int s  = d >> 12;
        const int mi = (d >> 11) & 1;
        const int kk = (d >> 6) & 31;
        const int l  = d & 63;
        const int m  = s * 32 + mi * 16 + (l & 15);
        const int k0 = kk * 32 + ((l >> 4) << 3);
        const float* sp = xt + (size_t)m * NII + k0;
        f32x4 a0 = *reinterpret_cast<const f32x4*>(sp);
        f32x4 a1 = *reinterpret_cast<const f32x4*>(sp + 4);
        short v[8];
        #pragma unroll
        for (int e = 0; e < 4; ++e) { v[e] = f2bf(a0[e]); v[4 + e] = f2bf(a1[e]); }
        *reinterpret_cast<bf16x8*>(dst + (size_t)d * 8) = *reinterpret_cast<bf16x8*>(v);
    }
}

// ---------------------------------------------------------------------------
// x_proj GEMM: gx[t][s][c][mi][l][8] bf16 in D-fragment layout.
// Block bx = tg*64 + cp: Wx slices for c = cp*2, cp*2+1 in LDS (128 KiB);
// 4 waves = (s, mi); 16 timesteps per block. 2048 blocks.
// ---------------------------------------------------------------------------
__global__ __launch_bounds__(256)
void xproj_gemm(const short* __restrict__ xpk, const short* __restrict__ wpk,
                short* __restrict__ gx)
{
    __shared__ short lds_wx[2][32768];   // 128 KiB

    const int tid = threadIdx.x;
    const int w = tid >> 6, l = tid & 63;
    const int tg = blockIdx.x >> 6, cp = blockIdx.x & 63;
    const int s = w >> 1, mi = w & 1;

    for (int cc = 0; cc < 2; ++cc) {
        const short* src = wpk + (size_t)(cp * 2 + cc) * 65536;   // x-half = first 32768
        #pragma unroll
        for (int i = 0; i < 16; ++i) {
            const int ch = tid + i * 256;
            *reinterpret_cast<bf16x8*>(&lds_wx[cc][(size_t)ch * 8]) =
                *reinterpret_cast<const bf16x8*>(&src[(size_t)ch * 8]);
        }
    }
    __syncthreads();

    for (int tt = 0; tt < 16; ++tt) {
        const int t = tg * 16 + tt;
        const short* apbase = xpk + (size_t)t * 65536
                            + ((size_t)((s * 2 + mi) * 32) * 64 + l) * 8;
        for (int cc = 0; cc < 2; ++cc) {
            f32x4 a00 = {0,0,0,0}, a01 = {0,0,0,0}, a10 = {0,0,0,0}, a11 = {0,0,0,0};
            const short* ap = apbase;
            const short* wl = &lds_wx[cc][(size_t)l * 8];
            #pragma unroll 4
            for (int kk = 0; kk < 32; kk += 2) {
                bf16x8 A0  = *reinterpret_cast<const bf16x8*>(ap);
                bf16x8 B00 = *reinterpret_cast<const bf16x8*>(wl);
                bf16x8 B01 = *reinterpret_cast<const bf16x8*>(wl + 512);
                bf16x8 A1  = *reinterpret_cast<const bf16x8*>(ap + 512);
                bf16x8 B10 = *reinterpret_cast<const bf16x8*>(wl + 1024);
                bf16x8 B11 = *reinterpret_cast<const bf16x8*>(wl + 1536);
                a00 = MFMA16(A0, B00, a00, 0, 0, 0);
                a01 = MFMA16(A0, B01, a01, 0, 0, 0);
                a10 = MFMA16(A1, B10, a10, 0, 0, 0);
                a11 = MFMA16(A1, B11, a11, 0, 0, 0);
                ap += 1024; wl += 2048;
            }
            short o[8];
            o[0] = f2bf(a00[0] + a10[0]); o[1] = f2bf(a00[1] + a10[1]);
            o[2] = f2bf(a00[2] + a10[2]); o[3] = f2bf(a00[3] + a10[3]);
            o[4] = f2bf(a01[0] + a11[0]); o[5] = f2bf(a01[1] + a11[1]);
            o[6] = f2bf(a01[2] + a11[2]); o[7] = f2bf(a01[3] + a11[3]);
            short* dst = gx + ((((size_t)t * 2 + s) * 128 + (size_t)(cp * 2 + cc)) * 2 + mi) * 512
                       + (size_t)l * 8;
            *reinterpret_cast<bf16x8*>(dst) = *reinterpret_cast<bf16x8*>(o);
        }
    }
}

// ---------------------------------------------------------------------------
// x-half compute (modes 0/1 fallback; verified r9).
// ---------------------------------------------------------------------------
__device__ __forceinline__ void compute_x_half(
    int t, int mi, int l, int s, int use_xpk,
    const float* __restrict__ x, const short* __restrict__ xpk,
    const short* lds_w, float* rdst)
{
    f32x4 a00 = {0,0,0,0}, a01 = {0,0,0,0}, a10 = {0,0,0,0}, a11 = {0,0,0,0};
    const short* wl = lds_w + (size_t)l * 8;
    if (use_xpk) {
        const short* ap = xpk + (size_t)t * 65536
                        + (((size_t)(s * 2 + mi)) * 32) * 512 + (size_t)l * 8;
        #pragma unroll 4
        for (int kk = 0; kk < 32; kk += 2) {
            bf16x8 A0  = *reinterpret_cast<const bf16x8*>(ap);
            bf16x8 B00 = *reinterpret_cast<const bf16x8*>(wl);
            bf16x8 B01 = *reinterpret_cast<const bf16x8*>(wl + 512);
            bf16x8 A1  = *reinterpret_cast<const bf16x8*>(ap + 512);
            bf16x8 B10 = *reinterpret_cast<const bf16x8*>(wl + 1024);
            bf16x8 B11 = *reinterpret_cast<const bf16x8*>(wl + 1536);
            a00 = MFMA16(A0, B00, a00, 0, 0, 0);
            a01 = MFMA16(A0, B01, a01, 0, 0, 0);
            a10 = MFMA16(A1, B10, a10, 0, 0, 0);
            a11 = MFMA16(A1, B11, a11, 0, 0, 0);
            ap += 1024; wl += 2048;
        }
    } else {
        const float* apf = x + ((size_t)t * BB + (size_t)(s * 32 + mi * 16 + (l & 15))) * NII
                         + ((l >> 4) << 3);
        #pragma unroll 4
        for (int kk = 0; kk < 32; kk += 2) {
            f32x4 f0 = *reinterpret_cast<const f32x4*>(apf);
            f32x4 f1 = *reinterpret_cast<const f32x4*>(apf + 4);
            bf16x8 B00 = *reinterpret_cast<const bf16x8*>(wl);
            bf16x8 B01 = *reinterpret_cast<const bf16x8*>(wl + 512);
            f32x4 f2 = *reinterpret_cast<const f32x4*>(apf + 32);
            f32x4 f3 = *reinterpret_cast<const f32x4*>(apf + 36);
            bf16x8 B10 = *reinterpret_cast<const bf16x8*>(wl + 1024);
            bf16x8 B11 = *reinterpret_cast<const bf16x8*>(wl + 1536);
            bf16x8 A0, A1;
            A0[0]=f2bf(f0[0]); A0[1]=f2bf(f0[1]); A0[2]=f2bf(f0[2]); A0[3]=f2bf(f0[3]);
            A0[4]=f2bf(f1[0]); A0[5]=f2bf(f1[1]); A0[6]=f2bf(f1[2]); A0[7]=f2bf(f1[3]);
            A1[0]=f2bf(f2[0]); A1[1]=f2bf(f2[1]); A1[2]=f2bf(f2[2]); A1[3]=f2bf(f2[3]);
            A1[4]=f2bf(f3[0]); A1[5]=f2bf(f3[1]); A1[6]=f2bf(f3[2]); A1[7]=f2bf(f3[3]);
            a00 = MFMA16(A0, B00, a00, 0, 0, 0);
            a01 = MFMA16(A0, B01, a01, 0, 0, 0);
            a10 = MFMA16(A1, B10, a10, 0, 0, 0);
            a11 = MFMA16(A1, B11, a11, 0, 0, 0);
            apf += 64; wl += 2048;
        }
    }
    rdst[0] = a00[0] + a10[0]; rdst[1] = a00[1] + a10[1];
    rdst[2] = a00[2] + a10[2]; rdst[3] = a00[3] + a10[3];
    rdst[4] = a01[0] + a11[0]; rdst[5] = a01[1] + a11[1];
    rdst[6] = a01[2] + a11[2]; rdst[7] = a01[3] + a11[3];
}

// ---------------------------------------------------------------------------
// Persistent LSTM, round-10.
//  mode 2: x precomputed in gx; all 4 waves = h (mi x K-half); gx prefetched.
//  mode 0/1: exact r9 behavior (x-waves 0,1; h-waves 2,3).
// ---------------------------------------------------------------------------
__global__ __launch_bounds__(256, 1)
void lstm_persistent(const float* __restrict__ x,
                     const short* __restrict__ xpk,
                     const short* __restrict__ wpk,
                     const short* __restrict__ gx,
                     const float* __restrict__ bfv, const float* __restrict__ biv,
                     const float* __restrict__ bcv, const float* __restrict__ bov,
                     float* __restrict__ out,
                     short* hpp,
                     unsigned* flags,
                     int mode)
{
    __shared__ short lds_w[64 * 2 * 64 * 8];   // 128 KiB weights
    __shared__ float redx[2][2][64][8];        // modes 0/1 only
    __shared__ float redh[4][64][8];
    __shared__ short hstage[256];
    __shared__ int   lds_epoch;

    const int tid = threadIdx.x;
    const int w   = tid >> 6;
    const int l   = tid & 63;
    const int c   = blockIdx.x >> 1;
    const int s   = blockIdx.x & 1;

    unsigned* flags_s = flags + s * 2048;      // 128 flags x 64 B stride

    if (mode == 2) {
        // stage only the h-half (64 KiB) at base 0
        const short* wsrc = wpk + (size_t)c * 65536 + 32768;
        #pragma unroll
        for (int i = 0; i < 16; ++i) {
            const int ch = tid + i * 256;
            *reinterpret_cast<bf16x8*>(&lds_w[(size_t)ch * 8]) =
                *reinterpret_cast<const bf16x8*>(&wsrc[(size_t)ch * 8]);
        }
    } else {
        const short* wsrc = wpk + (size_t)c * 65536;
        #pragma unroll
        for (int i = 0; i < 32; ++i) {
            const int ch = tid + i * 256;
            *reinterpret_cast<bf16x8*>(&lds_w[(size_t)ch * 8]) =
                *reinterpret_cast<const bf16x8*>(&wsrc[(size_t)ch * 8]);
        }
    }
    if (tid == 0) lds_epoch = -1;

    const int m_loc = tid >> 3;
    const int jc    = tid & 7;
    const int mi2   = m_loc >> 4, ml = m_loc & 15;
    const int lb    = (ml >> 2) << 4, lr = ml & 3;
    const int jcol  = c * 8 + jc;
    const int mrow  = s * 32 + m_loc;
    int lanes[4], es[4];
    #pragma unroll
    for (int g = 0; g < 4; ++g) { lanes[g] = lb + (g & 1) * 8 + jc; es[g] = (g >> 1) * 4 + lr; }

    float B4[4];
    B4[0] = bfv[jcol]; B4[1] = biv[jcol]; B4[2] = bcv[jcol]; B4[3] = bov[jcol];
    float cstate = 0.0f;
    __syncthreads();

    // prologues
    float gxv[4] = {0.f, 0.f, 0.f, 0.f};
    if (mode == 2) {
        const short* gsl = gx + ((((size_t)0 * 2 + s) * 128 + c) * 2 + mi2) * 512;
        #pragma unroll
        for (int g = 0; g < 4; ++g) gxv[g] = bf2f(gsl[(size_t)lanes[g] * 8 + es[g]]);
    } else if (w < 2) {
        compute_x_half(0, w & 1, l, s, mode, x, xpk, lds_w, &redx[0][w & 1][l][0]);
    }

    #pragma unroll 1
    for (int t = 0; t < TT; ++t) {
        const short* rcur = hpp + ((size_t)((t & 1) * 2 + s)) * HBUF_SHORTS;
        short*       rnxt = hpp + ((size_t)(((t + 1) & 1) * 2 + s)) * HBUF_SHORTS;

        if (mode == 2) {
            // ---- all 4 waves: wait, then h K-half MFMA ----
            if (w == 2) {
                const unsigned tv = (unsigned)t;
                for (;;) {
                    unsigned v0 = LD_AG(flags_s + (size_t)l * 16);
                    unsigned v1 = LD_AG(flags_s + (size_t)(l + 64) * 16);
                    if (__all((v0 >= tv) & (v1 >= tv))) break;
                    __builtin_amdgcn_s_sleep(1);
                }
                if (l == 0) *((volatile int*)&lds_epoch) = t;
            } else {
                while (*((volatile int*)&lds_epoch) < t) { }
            }
            asm volatile("" ::: "memory");

            const int mi = w & 1, ki = w >> 1;
            f32x4 a00 = {0,0,0,0}, a01 = {0,0,0,0}, a10 = {0,0,0,0}, a11 = {0,0,0,0};
            const short* ap = rcur + ((size_t)(mi * 32 + ki * 16) * 64 + l) * 8;
            const short* wl = &lds_w[(size_t)ki * 16384 + (size_t)l * 8];
            #pragma unroll 4
            for (int kk = 0; kk < 16; kk += 2) {
                bf16x8 A0  = ld_coh16(ap);
                bf16x8 B00 = *reinterpret_cast<const bf16x8*>(wl);
                bf16x8 B01 = *reinterpret_cast<const bf16x8*>(wl + 512);
                bf16x8 A1  = ld_coh16(ap + 512);
                bf16x8 B10 = *reinterpret_cast<const bf16x8*>(wl + 1024);
                bf16x8 B11 = *reinterpret_cast<const bf16x8*>(wl + 1536);
                a00 = MFMA16(A0, B00, a00, 0, 0, 0);
                a01 = MFMA16(A0, B01, a01, 0, 0, 0);
                a10 = MFMA16(A1, B10, a10, 0, 0, 0);
                a11 = MFMA16(A1, B11, a11, 0, 0, 0);
                ap += 1024; wl += 2048;
            }
            float* r = &redh[w][l][0];
            r[0] = a00[0] + a10[0]; r[1] = a00[1] + a10[1];
            r[2] = a00[2] + a10[2]; r[3] = a00[3] + a10[3];
            r[4] = a01[0] + a11[0]; r[5] = a01[1] + a11[1];
            r[6] = a01[2] + a11[2]; r[7] = a01[3] + a11[3];
        } else if (w >= 2) {
            // ---- r9 h-wave (full K) ----
            const int mi = w & 1;
            if (mi == 0) {
                const unsigned tv = (unsigned)t;
                for (;;) {
                    unsigned v0 = LD_AG(flags_s + (size_t)l * 16);
                    unsigned v1 = LD_AG(flags_s + (size_t)(l + 64) * 16);
                    if (__all((v0 >= tv) & (v1 >= tv))) break;
                    __builtin_amdgcn_s_sleep(1);
                }
                if (l == 0) *((volatile int*)&lds_epoch) = t;
            } else {
                while (*((volatile int*)&lds_epoch) < t) { }
            }
            asm volatile("" ::: "memory");

            f32x4 a00 = {0,0,0,0}, a01 = {0,0,0,0}, a10 = {0,0,0,0}, a11 = {0,0,0,0};
            const short* ap = rcur + ((size_t)(mi * 32)) * 512 + (size_t)l * 8;
            const short* wl = &lds_w[(size_t)32768 + (size_t)l * 8];
            #pragma unroll 4
            for (int kk = 0; kk < 32; kk += 2) {
                bf16x8 A0  = ld_coh16(ap);
                bf16x8 B00 = *reinterpret_cast<const bf16x8*>(wl);
                bf16x8 B01 = *reinterpret_cast<const bf16x8*>(wl + 512);
                bf16x8 A1  = ld_coh16(ap + 512);
                bf16x8 B10 = *reinterpret_cast<const bf16x8*>(wl + 1024);
                bf16x8 B11 = *reinterpret_cast<const bf16x8*>(wl + 1536);
                a00 = MFMA16(A0, B00, a00, 0, 0, 0);
                a01 = MFMA16(A0, B01, a01, 0, 0, 0);
                a10 = MFMA16(A1, B10, a10, 0, 0, 0);
                a11 = MFMA16(A1, B11, a11, 0, 0, 0);
                ap += 1024; wl += 2048;
            }
            float* r = &redh[2 + mi][l][0];
            r[0] = a00[0] + a10[0]; r[1] = a00[1] + a10[1];
            r[2] = a00[2] + a10[2]; r[3] = a00[3] + a10[3];
            r[4] = a01[0] + a11[0]; r[5] = a01[1] + a11[1];
            r[6] = a01[2] + a11[2]; r[7] = a01[3] + a11[3];
        } else {
            // ---- r9 x-wave prefetch ----
            if (t + 1 < TT)
                compute_x_half(t + 1, w & 1, l, s, mode, x, xpk, lds_w,
                               &redx[(t + 1) & 1][w & 1][l][0]);
        }
        __syncthreads();

        // epilogue
        float gv[4];
        #pragma unroll
        for (int g = 0; g < 4; ++g) {
            const int lane = lanes[g], e = es[g];
            float xterm = (mode == 2) ? (gxv[g] + redh[mi2][lane][e])
                                      : redx[t & 1][mi2][lane][e];
            gv[g] = xterm + redh[2 + mi2][lane][e] + B4[g];
        }
        const float F  = fast_sigmoid(gv[0]);
        const float I  = fast_sigmoid(gv[1]);
        const float Ct = fast_tanh(gv[2]);
        const float O  = fast_sigmoid(gv[3]);
        cstate = F * cstate + I * Ct;
        const float hn = O * fast_tanh(cstate);
        hstage[tid] = f2bf(hn);
        __syncthreads();

        // wave0 publishes packed H + flag (protocol verified r3-r9)
        if (w == 0 && t < TT - 1) {
            if (l < 32) {
                const int mi3 = l >> 4, ml3 = l & 15;
                const u64 v0 = ((const u64*)hstage)[l * 2];
                const u64 v1 = ((const u64*)hstage)[l * 2 + 1];
                const size_t sh = ((size_t)(mi3 * 32 + (c >> 2)) * 64
                                   + (size_t)((c & 3) * 16 + ml3)) * 8;
                u64* dq = (u64*)(rnxt + sh);
                ST_AG(dq, v0);
                ST_AG(dq + 1, v1);
            }
            asm volatile("s_waitcnt vmcnt(0)" ::: "memory");
            if (tid == 0)
                ST_AG(&flags_s[(size_t)c * 16], (unsigned)(t + 1));
        }

        // out/tail stores off the serial chain
        __builtin_nontemporal_store(hn, &out[(size_t)t * BB * NHH + (size_t)mrow * NHH + jcol]);
        if (t == TT - 1) {
            float* tail = out + (size_t)TT * BB * NHH;
            tail[(size_t)mrow * NHH + jcol]                    = hn;
            tail[(size_t)BB * NHH + (size_t)mrow * NHH + jcol] = cstate;
        }

        // prefetch next step's gx during the slack
        if (mode == 2 && t + 1 < TT) {
            const short* gsl = gx + ((((size_t)(t + 1) * 2 + s) * 128 + c) * 2 + mi2) * 512;
            #pragma unroll
            for (int g = 0; g < 4; ++g) gxv[g] = bf2f(gsl[(size_t)lanes[g] * 8 + es[g]]);
        }
    }
}

extern "C" void kernel_launch(void* const* d_in, const int* in_sizes, int n_in,
                              void* d_out, int out_size, void* d_ws, size_t ws_size,
                              hipStream_t stream) {
    const float* inputs = (const float*)d_in[0];
    const float* Wxf = (const float*)d_in[1],  *Whf = (const float*)d_in[2],  *bf = (const float*)d_in[3];
    const float* Wxi = (const float*)d_in[4],  *Whi = (const float*)d_in[5],  *bi = (const float*)d_in[6];
    const float* Wxc = (const float*)d_in[7],  *Whc = (const float*)d_in[8],  *bc = (const float*)d_in[9];
    const float* Wxo = (const float*)d_in[10], *Who = (const float*)d_in[11], *bo = (const float*)d_in[12];

    float* out = (float*)d_out;
    char*  wsb = (char*)d_ws;

    short*    wpk   = (short*)wsb;
    unsigned* flags = (unsigned*)(wsb + WPK_BYTES);
    short*    hpp   = (short*)(wsb + WPK_BYTES + FLG_BYTES);
    short*    xpk   = (short*)(wsb + WPK_BYTES + FLG_BYTES + HPP_BYTES);
    short*    gx    = (short*)(wsb + WPK_BYTES + FLG_BYTES + HPP_BYTES + XPK_BYTES);

    const size_t needT1 = WPK_BYTES + FLG_BYTES + HPP_BYTES + XPK_BYTES;
    const size_t needT0 = needT1 + GX_BYTES;
    const int mode = (ws_size >= needT0) ? 2 : (ws_size >= needT1) ? 1 : 0;

    // zero flags + H ping-pong every launch (graph replays rerun this)
    hipMemsetAsync(flags, 0, FLG_BYTES + HPP_BYTES, stream);

    pack_weights_kernel<<<dim3(128), dim3(256), 0, stream>>>(
        Wxf, Whf, Wxi, Whi, Wxc, Whc, Wxo, Who, wpk);

    if (mode >= 1)
        pack_x_kernel<<<dim3(TT), dim3(256), 0, stream>>>(inputs, xpk);

    if (mode == 2)
        xproj_gemm<<<dim3(2048), dim3(256), 0, stream>>>(xpk, wpk, gx);

    // ~145 KiB static LDS -> 1 block/CU -> 256 blocks co-resident;
    // two independent 128-block sync domains (batch halves).
    lstm_persistent<<<dim3(NBLK), dim3(256), 0, stream>>>(
        inputs, xpk, wpk, gx, bf, bi, bc, bo, out, hpp, flags, mode);
}